// Round 3
// baseline (50956.522 us; speedup 1.0000x reference)
//
#include <hip/hip_runtime.h>
#include <cstdint>

#define B_  128
#define T_  1024
#define DIN 13
#define HS  256
#define N0  77
#define N1  51
#define N2  128

// gate z layout (f16 elems): [x 0..12, pad..15 | l0o 16..92 | l1o 93..143 | l2o 144..271]
#define K2G 136
#define QG  34
#define NRG 1024

// z0: [x 0..12 pad..15 | h[0:77] 16..92 pad..95]   -> 12 quads
#define Q0   12
#define NR0  308
// z1: [h[77:128] 0..50 pad..63 | l0o 64..140 pad..143] -> 18 quads
#define Q1N  18
#define NR1  204
// z2: [h[128:256] 0..127 | l1o 128..178 pad..183] -> 23 quads
#define Q2N  23
#define NR2  512

typedef _Float16 h2_t __attribute__((ext_vector_type(2)));

static __device__ __forceinline__ uint32_t pk2(float a, float b) {
  h2_t v; v.x = (_Float16)a; v.y = (_Float16)b;
  return __builtin_bit_cast(uint32_t, v);
}
static __device__ __forceinline__ unsigned short f16b(float v) {
  return __builtin_bit_cast(unsigned short, (_Float16)v);
}
static __device__ __forceinline__ void st16(void* base, int idx, unsigned short v) {
  ((unsigned short*)base)[idx] = v;
}
static __device__ __forceinline__ float dot2f(uint32_t w, uint32_t z, float acc) {
#if __has_builtin(__builtin_amdgcn_fdot2)
  return __builtin_amdgcn_fdot2(__builtin_bit_cast(h2_t, w), __builtin_bit_cast(h2_t, z), acc, false);
#else
  h2_t a = __builtin_bit_cast(h2_t, w), b = __builtin_bit_cast(h2_t, z);
  return acc + (float)a.x * (float)b.x + (float)a.y * (float)b.y;
#endif
}
static __device__ __forceinline__ float dot8f(uint4 w, uint4 z, float acc) {
  acc = dot2f(w.x, z.x, acc);
  acc = dot2f(w.y, z.y, acc);
  acc = dot2f(w.z, z.z, acc);
  acc = dot2f(w.w, z.w, acc);
  return acc;
}
static __device__ __forceinline__ float sigf(float x) { return 1.f / (1.f + expf(-x)); }

// ---------------- prep kernels: f32 -> packed f16, quad-interleaved [q][row][4] ----------------

__global__ void prep_gates2(const float* __restrict__ Wih, const float* __restrict__ Whh,
                            uint32_t* __restrict__ out) {
  int id = blockIdx.x * blockDim.x + threadIdx.x;
  if (id >= K2G * NRG) return;
  int k2 = id >> 10, row = id & (NRG - 1);
  float v[2];
#pragma unroll
  for (int j = 0; j < 2; ++j) {
    int e = 2 * k2 + j;
    float val = 0.f;
    if (e < DIN) val = Wih[row * DIN + e];
    else if (e >= 16 && e < 272) val = Whh[row * HS + (e - 16)];
    v[j] = val;
  }
  out[((k2 >> 2) * NRG + row) * 4 + (k2 & 3)] = pk2(v[0], v[1]);
}

__global__ void prep_cfc2(const float* __restrict__ Wf1, const float* __restrict__ Wf2,
                          const float* __restrict__ Wta, const float* __restrict__ Wtb,
                          const float* __restrict__ mask,
                          int nh, int K, int NR, int K2,
                          int p0n, int p0c, int p1s, int p1n, int p1c,
                          uint32_t* __restrict__ out) {
  int id = blockIdx.x * blockDim.x + threadIdx.x;
  if (id >= NR * K2) return;
  int k2 = id / NR, r = id % NR;
  int mat = r / nh, o = r % nh;
  const float* W = (mat == 0) ? Wf1 : (mat == 1) ? Wf2 : (mat == 2) ? Wta : Wtb;
  float v[2];
#pragma unroll
  for (int j = 0; j < 2; ++j) {
    int e = 2 * k2 + j;
    int col = -1;
    if (e < p0n) col = p0c + e;
    else if (e >= p1s && e < p1s + p1n) col = p1c + (e - p1s);
    float val = 0.f;
    if (col >= 0) {
      val = W[o * K + col];
      if (mat < 2) val *= mask[o * K + col];
    }
    v[j] = val;
  }
  out[((k2 >> 2) * NR + r) * 4 + (k2 & 3)] = pk2(v[0], v[1]);
}

// ---------------- shared structs ----------------

struct Args {
  const float* x;
  const float* Wih; const float* Whh; const float* bih; const float* bhh;
  const float* W0[4]; const float* b0[4]; const float* m0;
  const float* W1[4]; const float* b1[4]; const float* m1;
  const float* W2[4]; const float* b2[4]; const float* m2;
  const float* gW; const float* gb; const float* aW; const float* ab;
  const float* uW; const float* ub;
  const uint4* wsG; const uint4* wsL0; const uint4* wsL1; const uint4* wsL2;
  float* out;
};

// ================= pipelined single-WG persistent kernel =================

struct SMP {
  uint4 l0w[Q0 * NR0];    // 59136 B
  uint4 l1w[Q1N * NR1];   // 58752 B
  uint4 zb[2][QG];        // gate-input z, ping-pong (f16)
  uint4 z0[Q0];
  uint4 z1[Q1N];
  uint4 z2[Q2N];
  float garr[1024];
  float ffb[512];
  float cb0[NR0];
  float cb1[NR1];
  uint4 hwq[12][16];      // head weights packed to match zb l2o region
  float hb[12];
};
static_assert(sizeof(SMP) <= 163840, "SMP too big");

__global__ __launch_bounds__(512) void rnn_pipe(Args A) {
  extern __shared__ char smraw[];
  SMP& sm = *(SMP*)smraw;
  const int tid = threadIdx.x;
  const int b = blockIdx.x;
  const float* xb = A.x + (size_t)b * T_ * DIN;
  const size_t UNC_OFF = (size_t)B_ * T_ * 6;

  // ---- startup ----
  for (int i = tid; i < Q0 * NR0; i += 512) sm.l0w[i] = A.wsL0[i];
  for (int i = tid; i < Q1N * NR1; i += 512) sm.l1w[i] = A.wsL1[i];
  for (int i = tid; i < NR0; i += 512) sm.cb0[i] = A.b0[i / N0][i % N0];
  for (int i = tid; i < NR1; i += 512) sm.cb1[i] = A.b1[i / N1][i % N1];
  for (int i = tid; i < 768; i += 512) {
    int r = i >> 6, w = i & 63;
    const float* W = (r < 3) ? A.gW + r * 128 : (r < 6) ? A.aW + (r - 3) * 128 : A.uW + (r - 6) * 128;
    ((uint32_t*)sm.hwq)[i] = pk2(W[2 * w], W[2 * w + 1]);
  }
  if (tid < 12) sm.hb[tid] = (tid < 3) ? A.gb[tid] : (tid < 6) ? A.ab[tid - 3] : A.ub[tid - 6];
  {
    uint32_t* zz = (uint32_t*)sm.zb;
    for (int i = tid; i < (2 * QG + Q0 + Q1N + Q2N) * 4; i += 512) zz[i] = 0u;
  }

  // register-resident weights
  uint4 gwr[16];   // gate quads 26..33 for rows tid, tid+512
#pragma unroll
  for (int q = 0; q < 8; ++q) {
    gwr[q]     = A.wsG[(26 + q) * NRG + tid];
    gwr[8 + q] = A.wsG[(26 + q) * NRG + 512 + tid];
  }
  uint4 l2r[23];   // l2 row tid, all 23 quads
#pragma unroll
  for (int q = 0; q < Q2N; ++q) l2r[q] = A.wsL2[q * NR2 + tid];

  const float cbr = A.b2[tid >> 7][tid & 127];
  const float bgA = A.bih[tid] + A.bhh[tid];
  const float bgB = A.bih[tid + 512] + A.bhh[tid + 512];
  float c_r = 0.f;
  __syncthreads();

  // x(0) into zb[0]
  if (tid < 16) st16(sm.zb[0], tid, f16b(tid < DIN ? xb[tid] : 0.f));
  __syncthreads();

  // prologue: gates partial for t=0 (quads 0..17; h regions are zero)
  float accA = bgA, accB = bgB;
#pragma unroll
  for (int q = 0; q < 18; ++q) {
    uint4 z = sm.zb[0][q];
    accA = dot8f(A.wsG[q * NRG + tid], z, accA);
    accB = dot8f(A.wsG[q * NRG + 512 + tid], z, accB);
  }

  for (int t = 0; t < T_; ++t) {
    const int cur = t & 1, nxt = cur ^ 1;

    // ---- P1: gates final (quads 18..25 streamed, 26..33 from regs) ----
#pragma unroll
    for (int q = 0; q < 8; ++q) {
      uint4 z = sm.zb[cur][18 + q];
      accA = dot8f(A.wsG[(18 + q) * NRG + tid], z, accA);
      accB = dot8f(A.wsG[(18 + q) * NRG + 512 + tid], z, accB);
    }
#pragma unroll
    for (int q = 0; q < 8; ++q) {
      uint4 z = sm.zb[cur][26 + q];
      accA = dot8f(gwr[q], z, accA);
      accB = dot8f(gwr[8 + q], z, accB);
    }
    sm.garr[tid] = accA;
    sm.garr[512 + tid] = accB;
    __syncthreads();

    // ---- P2: LSTM (threads 0..255) + heads for t-1 (threads 256..267) ----
    if (tid < 256) {
      float gi = sm.garr[tid], gf = sm.garr[256 + tid];
      float gg = sm.garr[512 + tid], go = sm.garr[768 + tid];
      float cn = sigf(gf) * c_r + sigf(gi) * tanhf(gg);
      c_r = cn;
      float h = sigf(go) * tanhf(cn);
      unsigned short hb16 = f16b(h);
      if (tid < N0)            st16(sm.z0, 16 + tid, hb16);
      else if (tid < 128)      st16(sm.z1, tid - N0, hb16);
      else                     st16(sm.z2, tid - 128, hb16);
    } else if (tid < 268 && t > 0) {
      int r = tid - 256;
      float a = sm.hb[r];
#pragma unroll
      for (int q = 0; q < 16; ++q) a = dot8f(sm.hwq[r][q], sm.zb[cur][18 + q], a);
      size_t base = ((size_t)b * T_ + (t - 1)) * 6;
      if (r < 6) A.out[base + r] = a;
      else {
        float sp = (a > 0.f) ? (a + log1pf(expf(-a))) : log1pf(expf(a));
        A.out[UNC_OFF + base + (r - 6)] = sp;
      }
    }
    __syncthreads();

    // ---- P3: l0 fused matvec+combine (77 threads) ----
    if (tid < N0) {
      float a0 = sm.cb0[tid], a1 = sm.cb0[N0 + tid];
      float a2 = sm.cb0[2 * N0 + tid], a3 = sm.cb0[3 * N0 + tid];
#pragma unroll
      for (int q = 0; q < Q0; ++q) {
        uint4 z = sm.z0[q];
        a0 = dot8f(sm.l0w[q * NR0 + tid], z, a0);
        a1 = dot8f(sm.l0w[q * NR0 + N0 + tid], z, a1);
        a2 = dot8f(sm.l0w[q * NR0 + 2 * N0 + tid], z, a2);
        a3 = dot8f(sm.l0w[q * NR0 + 3 * N0 + tid], z, a3);
      }
      float ti = sigf(a2 + a3);
      float v = tanhf(a0) * (1.f - ti) + ti * tanhf(a1);
      unsigned short v16 = f16b(v);
      st16(sm.z1, 64 + tid, v16);
      st16(sm.zb[nxt], 16 + tid, v16);
    }
    __syncthreads();

    // ---- P4: l1 fused (51 threads) + x(t+1) prefetch (threads 64..79) ----
    if (tid < N1) {
      float a0 = sm.cb1[tid], a1 = sm.cb1[N1 + tid];
      float a2 = sm.cb1[2 * N1 + tid], a3 = sm.cb1[3 * N1 + tid];
#pragma unroll
      for (int q = 0; q < Q1N; ++q) {
        uint4 z = sm.z1[q];
        a0 = dot8f(sm.l1w[q * NR1 + tid], z, a0);
        a1 = dot8f(sm.l1w[q * NR1 + N1 + tid], z, a1);
        a2 = dot8f(sm.l1w[q * NR1 + 2 * N1 + tid], z, a2);
        a3 = dot8f(sm.l1w[q * NR1 + 3 * N1 + tid], z, a3);
      }
      float ti = sigf(a2 + a3);
      float v = tanhf(a0) * (1.f - ti) + ti * tanhf(a1);
      unsigned short v16 = f16b(v);
      st16(sm.z2, 128 + tid, v16);
      st16(sm.zb[nxt], 93 + tid, v16);
    } else if (tid >= 64 && tid < 80) {
      int i = tid - 64;
      float v = (t + 1 < T_ && i < DIN) ? xb[(size_t)(t + 1) * DIN + i] : 0.f;
      unsigned short v16 = f16b(v);
      st16(sm.zb[nxt], i, v16);
      st16(sm.z0, i, v16);
    }
    __syncthreads();

    // ---- P5: mega-stream: gates partial (t+1, quads 0..17) + l2 (regs) ----
    accA = bgA; accB = bgB;
#pragma unroll
    for (int q = 0; q < 18; ++q) {
      uint4 z = sm.zb[nxt][q];
      accA = dot8f(A.wsG[q * NRG + tid], z, accA);
      accB = dot8f(A.wsG[q * NRG + 512 + tid], z, accB);
    }
    {
      float a = cbr;
#pragma unroll
      for (int q = 0; q < Q2N; ++q) a = dot8f(l2r[q], sm.z2[q], a);
      sm.ffb[tid] = (tid < 256) ? tanhf(a) : a;
    }
    __syncthreads();

    // ---- P6: l2 combine (128 threads) ----
    if (tid < 128) {
      float ti = sigf(sm.ffb[256 + tid] + sm.ffb[384 + tid]);
      float v = sm.ffb[tid] * (1.f - ti) + ti * sm.ffb[128 + tid];
      st16(sm.zb[nxt], 144 + tid, f16b(v));
    }
    __syncthreads();
  }

  // ---- tail: heads for t = T_-1 (l2o in zb[0]) ----
  if (tid >= 256 && tid < 268) {
    int r = tid - 256;
    float a = sm.hb[r];
#pragma unroll
    for (int q = 0; q < 16; ++q) a = dot8f(sm.hwq[r][q], sm.zb[0][18 + q], a);
    size_t base = ((size_t)b * T_ + (T_ - 1)) * 6;
    if (r < 6) A.out[base + r] = a;
    else {
      float sp = (a > 0.f) ? (a + log1pf(expf(-a))) : log1pf(expf(a));
      A.out[UNC_OFF + base + (r - 6)] = sp;
    }
  }
}

// ================= fallback: direct f32 kernel (no workspace) =================

struct SMF {
  float xt[16];
  float lstm_h[HS];
  float hprev[HS];
  float garr[4 * HS];
  float ffb[4][128];
  float cb0[NR0];
  float cb1[NR1];
  float cb2[NR2];
  float hw[12][132];
  float hb[12];
};

__global__ __launch_bounds__(512, 1) void rnn_fallback(Args A) {
  extern __shared__ char smraw[];
  SMF& sm = *(SMF*)smraw;
  const int tid = threadIdx.x;
  const int b = blockIdx.x;

  for (int i = tid; i < NR0; i += 512) sm.cb0[i] = A.b0[i / N0][i % N0];
  for (int i = tid; i < NR1; i += 512) sm.cb1[i] = A.b1[i / N1][i % N1];
  for (int i = tid; i < NR2; i += 512) sm.cb2[i] = A.b2[i / N2][i % N2];
  for (int i = tid; i < 12 * 128; i += 512) {
    int r = i >> 7, k = i & 127;
    sm.hw[r][k] = (r < 3) ? A.gW[r * 128 + k]
                : (r < 6) ? A.aW[(r - 3) * 128 + k]
                          : A.uW[(r - 6) * 128 + k];
  }
  if (tid < 12) sm.hb[tid] = (tid < 3) ? A.gb[tid] : (tid < 6) ? A.ab[tid - 3] : A.ub[tid - 6];
  for (int i = tid; i < HS; i += 512) sm.hprev[i] = 0.f;
  float bga = A.bih[tid] + A.bhh[tid];
  float bgb = A.bih[tid + 512] + A.bhh[tid + 512];
  float c_r = 0.f;
  __syncthreads();

  const float* xb = A.x + (size_t)b * T_ * DIN;
  const size_t UNC_OFF = (size_t)B_ * T_ * 6;

  for (int t = 0; t < T_; ++t) {
    const float* xp = xb + (size_t)t * DIN;
    if (tid < DIN) sm.xt[tid] = xp[tid];
    __syncthreads();

    float aa = bga, ab = bgb;
    for (int k = 0; k < DIN; ++k) {
      float xv = sm.xt[k];
      aa += A.Wih[tid * DIN + k] * xv;
      ab += A.Wih[(tid + 512) * DIN + k] * xv;
    }
    for (int k = 0; k < HS; ++k) {
      float hv = sm.hprev[k];
      aa += A.Whh[tid * HS + k] * hv;
      ab += A.Whh[(tid + 512) * HS + k] * hv;
    }
    sm.garr[tid] = aa;
    sm.garr[tid + 512] = ab;
    __syncthreads();

    if (tid < HS) {
      float gi = sm.garr[tid], gf = sm.garr[HS + tid];
      float gg = sm.garr[2 * HS + tid], go = sm.garr[3 * HS + tid];
      float cn = sigf(gf) * c_r + sigf(gi) * tanhf(gg);
      c_r = cn;
      sm.lstm_h[tid] = sigf(go) * tanhf(cn);
    }
    __syncthreads();

    if (tid < NR0) {
      int mat = tid / N0, o = tid % N0;
      const float* W = A.W0[mat];
      const float* m = A.m0;
      const int Kl = DIN + N0;
      float acc = sm.cb0[tid];
      for (int k = 0; k < DIN; ++k) {
        float w = W[o * Kl + k];
        if (mat < 2) w *= m[o * Kl + k];
        acc += w * sm.xt[k];
      }
      for (int k = DIN; k < Kl; ++k) acc += W[o * Kl + k] * sm.lstm_h[k - DIN];
      sm.ffb[mat][o] = (mat < 2) ? tanhf(acc) : acc;
    }
    __syncthreads();
    if (tid < N0) {
      float ti = sigf(sm.ffb[2][tid] + sm.ffb[3][tid]);
      sm.hprev[tid] = sm.ffb[0][tid] * (1.f - ti) + ti * sm.ffb[1][tid];
    }
    __syncthreads();

    if (tid < NR1) {
      int mat = tid / N1, o = tid % N1;
      const float* W = A.W1[mat];
      const float* m = A.m1;
      const int Kl = N0 + N1;
      float acc = sm.cb1[tid];
      for (int k = 0; k < N0; ++k) {
        float w = W[o * Kl + k];
        if (mat < 2) w *= m[o * Kl + k];
        acc += w * sm.hprev[k];
      }
      for (int k = N0; k < Kl; ++k) acc += W[o * Kl + k] * sm.lstm_h[k];
      sm.ffb[mat][o] = (mat < 2) ? tanhf(acc) : acc;
    }
    __syncthreads();
    if (tid < N1) {
      float ti = sigf(sm.ffb[2][tid] + sm.ffb[3][tid]);
      sm.hprev[N0 + tid] = sm.ffb[0][tid] * (1.f - ti) + ti * sm.ffb[1][tid];
    }
    __syncthreads();

    {
      int mat = tid >> 7, o = tid & 127;
      const float* W = A.W2[mat];
      const float* m = A.m2;
      const int Kl = N1 + N2;
      float acc = sm.cb2[tid];
      for (int k = 0; k < N1; ++k) {
        float w = W[o * Kl + k];
        if (mat < 2) w *= m[o * Kl + k];
        acc += w * sm.hprev[N0 + k];
      }
      for (int k = N1; k < Kl; ++k) acc += W[o * Kl + k] * sm.lstm_h[N0 + k];
      sm.ffb[mat][o] = (mat < 2) ? tanhf(acc) : acc;
    }
    __syncthreads();
    if (tid < N2) {
      float ti = sigf(sm.ffb[2][tid] + sm.ffb[3][tid]);
      sm.hprev[N0 + N1 + tid] = sm.ffb[0][tid] * (1.f - ti) + ti * sm.ffb[1][tid];
    }
    __syncthreads();

    if (tid >= 256 && tid < 268) {
      int r = tid - 256;
      const float* mo = &sm.hprev[N0 + N1];
      float acc = sm.hb[r];
      for (int k = 0; k < 128; ++k) acc += sm.hw[r][k] * mo[k];
      size_t base = ((size_t)b * T_ + t) * 6;
      if (r < 6) A.out[base + r] = acc;
      else {
        float sp = (acc > 0.f) ? (acc + log1pf(expf(-acc))) : log1pf(expf(acc));
        A.out[UNC_OFF + base + (r - 6)] = sp;
      }
    }
    __syncthreads();
  }
}

// ---------------- launcher ----------------

extern "C" void kernel_launch(void* const* d_in, const int* in_sizes, int n_in,
                              void* d_out, int out_size, void* d_ws, size_t ws_size,
                              hipStream_t stream) {
  Args A;
  A.x   = (const float*)d_in[0];
  A.Wih = (const float*)d_in[1];
  A.Whh = (const float*)d_in[2];
  A.bih = (const float*)d_in[3];
  A.bhh = (const float*)d_in[4];
  const float** Wl[3] = {A.W0, A.W1, A.W2};
  const float** bl[3] = {A.b0, A.b1, A.b2};
  const float* ml[3];
  for (int l = 0; l < 3; ++l) {
    int base = 5 + l * 9;
    for (int nm = 0; nm < 4; ++nm) {
      Wl[l][nm] = (const float*)d_in[base + 2 * nm];
      bl[l][nm] = (const float*)d_in[base + 2 * nm + 1];
    }
    ml[l] = (const float*)d_in[base + 8];
  }
  A.m0 = ml[0]; A.m1 = ml[1]; A.m2 = ml[2];
  A.gW = (const float*)d_in[32];
  A.gb = (const float*)d_in[33];
  A.aW = (const float*)d_in[34];
  A.ab = (const float*)d_in[35];
  A.uW = (const float*)d_in[36];
  A.ub = (const float*)d_in[37];
  A.out = (float*)d_out;

  const size_t szG  = (size_t)QG * NRG * 16;    // 557056
  const size_t szL0 = (size_t)Q0 * NR0 * 16;    // 59136
  const size_t szL1 = (size_t)Q1N * NR1 * 16;   // 58752
  const size_t szL2 = (size_t)Q2N * NR2 * 16;   // 188416
  const size_t offG = 0, offL0 = szG, offL1 = offL0 + szL0, offL2 = offL1 + szL1;
  const size_t need = offL2 + szL2;             // 863360

  char* ws = (char*)d_ws;
  A.wsG  = (const uint4*)(ws + offG);
  A.wsL0 = (const uint4*)(ws + offL0);
  A.wsL1 = (const uint4*)(ws + offL1);
  A.wsL2 = (const uint4*)(ws + offL2);

  if (ws_size >= need) {
    int n;
    n = K2G * NRG;
    prep_gates2<<<(n + 255) / 256, 256, 0, stream>>>(A.Wih, A.Whh, (uint32_t*)(ws + offG));
    n = NR0 * 48;
    prep_cfc2<<<(n + 255) / 256, 256, 0, stream>>>(A.W0[0], A.W0[1], A.W0[2], A.W0[3], A.m0,
                                                   N0, DIN + N0, NR0, 48,
                                                   13, 0, 16, 77, 13,
                                                   (uint32_t*)(ws + offL0));
    n = NR1 * 72;
    prep_cfc2<<<(n + 255) / 256, 256, 0, stream>>>(A.W1[0], A.W1[1], A.W1[2], A.W1[3], A.m1,
                                                   N1, N0 + N1, NR1, 72,
                                                   51, 77, 64, 77, 0,
                                                   (uint32_t*)(ws + offL1));
    n = NR2 * 92;
    prep_cfc2<<<(n + 255) / 256, 256, 0, stream>>>(A.W2[0], A.W2[1], A.W2[2], A.W2[3], A.m2,
                                                   N2, N1 + N2, NR2, 92,
                                                   128, 51, 128, 51, 0,
                                                   (uint32_t*)(ws + offL2));
    hipFuncSetAttribute(reinterpret_cast<const void*>(&rnn_pipe),
                        hipFuncAttributeMaxDynamicSharedMemorySize, (int)sizeof(SMP));
    rnn_pipe<<<B_, 512, sizeof(SMP), stream>>>(A);
  } else {
    hipFuncSetAttribute(reinterpret_cast<const void*>(&rnn_fallback),
                        hipFuncAttributeMaxDynamicSharedMemorySize, (int)sizeof(SMF));
    rnn_fallback<<<B_, 512, sizeof(SMF), stream>>>(A);
  }
}

// Round 4
// 12111.227 us; speedup vs baseline: 4.2074x; 4.2074x over previous
//
#include <hip/hip_runtime.h>
#include <cstdint>

#define B_  128
#define T_  1024
#define DIN 13
#define HS  256
#define N0  77
#define N1  51
#define N2  128

// gate z layout (f16 elems): [x 0..12, pad..15 | l0o 16..92 | l1o 93..143 | l2o 144..271]
#define K2G 136
#define QG  34
#define NRG 1024

// z0: [x 0..12 pad..15 | h[0:77] 16..92 pad..95]   -> 12 quads
#define Q0   12
#define NR0  308
// z1: [h[77:128] 0..50 pad..63 | l0o 64..140 pad..143] -> 18 quads
#define Q1N  18
#define NR1  204
// z2: [h[128:256] 0..127 | l1o 128..178 pad..183] -> 23 quads
#define Q2N  23
#define NR2  512

typedef _Float16 h2_t __attribute__((ext_vector_type(2)));

static __device__ __forceinline__ uint32_t pk2(float a, float b) {
  h2_t v; v.x = (_Float16)a; v.y = (_Float16)b;
  return __builtin_bit_cast(uint32_t, v);
}
static __device__ __forceinline__ unsigned short f16b(float v) {
  return __builtin_bit_cast(unsigned short, (_Float16)v);
}
static __device__ __forceinline__ void st16(void* base, int idx, unsigned short v) {
  ((unsigned short*)base)[idx] = v;
}
static __device__ __forceinline__ float dot2f(uint32_t w, uint32_t z, float acc) {
#if __has_builtin(__builtin_amdgcn_fdot2)
  return __builtin_amdgcn_fdot2(__builtin_bit_cast(h2_t, w), __builtin_bit_cast(h2_t, z), acc, false);
#else
  h2_t a = __builtin_bit_cast(h2_t, w), b = __builtin_bit_cast(h2_t, z);
  return acc + (float)a.x * (float)b.x + (float)a.y * (float)b.y;
#endif
}
static __device__ __forceinline__ float dot8f(uint4 w, uint4 z, float acc) {
  acc = dot2f(w.x, z.x, acc);
  acc = dot2f(w.y, z.y, acc);
  acc = dot2f(w.z, z.z, acc);
  acc = dot2f(w.w, z.w, acc);
  return acc;
}
static __device__ __forceinline__ float sigf(float x) { return 1.f / (1.f + expf(-x)); }

// ---------------- prep kernels: f32 -> packed f16, quad-interleaved [q][row][4] ----------------

__global__ void prep_gates2(const float* __restrict__ Wih, const float* __restrict__ Whh,
                            uint32_t* __restrict__ out) {
  int id = blockIdx.x * blockDim.x + threadIdx.x;
  if (id >= K2G * NRG) return;
  int k2 = id >> 10, row = id & (NRG - 1);
  float v[2];
#pragma unroll
  for (int j = 0; j < 2; ++j) {
    int e = 2 * k2 + j;
    float val = 0.f;
    if (e < DIN) val = Wih[row * DIN + e];
    else if (e >= 16 && e < 272) val = Whh[row * HS + (e - 16)];
    v[j] = val;
  }
  out[((k2 >> 2) * NRG + row) * 4 + (k2 & 3)] = pk2(v[0], v[1]);
}

__global__ void prep_cfc2(const float* __restrict__ Wf1, const float* __restrict__ Wf2,
                          const float* __restrict__ Wta, const float* __restrict__ Wtb,
                          const float* __restrict__ mask,
                          int nh, int K, int NR, int K2,
                          int p0n, int p0c, int p1s, int p1n, int p1c,
                          uint32_t* __restrict__ out) {
  int id = blockIdx.x * blockDim.x + threadIdx.x;
  if (id >= NR * K2) return;
  int k2 = id / NR, r = id % NR;
  int mat = r / nh, o = r % nh;
  const float* W = (mat == 0) ? Wf1 : (mat == 1) ? Wf2 : (mat == 2) ? Wta : Wtb;
  float v[2];
#pragma unroll
  for (int j = 0; j < 2; ++j) {
    int e = 2 * k2 + j;
    int col = -1;
    if (e < p0n) col = p0c + e;
    else if (e >= p1s && e < p1s + p1n) col = p1c + (e - p1s);
    float val = 0.f;
    if (col >= 0) {
      val = W[o * K + col];
      if (mat < 2) val *= mask[o * K + col];
    }
    v[j] = val;
  }
  out[((k2 >> 2) * NR + r) * 4 + (k2 & 3)] = pk2(v[0], v[1]);
}

// ---------------- shared structs ----------------

struct Args {
  const float* x;
  const float* Wih; const float* Whh; const float* bih; const float* bhh;
  const float* W0[4]; const float* b0[4]; const float* m0;
  const float* W1[4]; const float* b1[4]; const float* m1;
  const float* W2[4]; const float* b2[4]; const float* m2;
  const float* gW; const float* gb; const float* aW; const float* ab;
  const float* uW; const float* ub;
  const uint4* wsG; const uint4* wsL0; const uint4* wsL1; const uint4* wsL2;
  float* out;
};

// ================= pipelined single-WG persistent kernel =================

struct SMP {
  uint4 l0w[Q0 * NR0];    // 59136 B
  uint4 l1w[Q1N * NR1];   // 58752 B
  uint4 zb[2][QG];        // gate-input z, ping-pong (f16)
  uint4 z0[Q0];
  uint4 z1[Q1N];
  uint4 z2[Q2N];
  float garr[1024];
  float ffb[512];
  float cb0[NR0];
  float cb1[NR1];
  uint4 hwq[12][16];      // head weights packed to match zb l2o region
  float hb[12];
};
static_assert(sizeof(SMP) <= 163840, "SMP too big");

// 512 threads = 8 waves = 2 waves/SIMD -> VGPR cap 256. Register arrays
// gwr[16]+l2r[23] = 156 VGPRs MUST stay in registers: round-3's
// __launch_bounds__(512) capped at 128 and spilled 39 GB/launch to scratch.
__global__ __launch_bounds__(512, 2) void rnn_pipe(Args A) {
  extern __shared__ char smraw[];
  SMP& sm = *(SMP*)smraw;
  const int tid = threadIdx.x;
  const int b = blockIdx.x;
  const float* xb = A.x + (size_t)b * T_ * DIN;
  const size_t UNC_OFF = (size_t)B_ * T_ * 6;

  // ---- startup ----
  for (int i = tid; i < Q0 * NR0; i += 512) sm.l0w[i] = A.wsL0[i];
  for (int i = tid; i < Q1N * NR1; i += 512) sm.l1w[i] = A.wsL1[i];
  for (int i = tid; i < NR0; i += 512) sm.cb0[i] = A.b0[i / N0][i % N0];
  for (int i = tid; i < NR1; i += 512) sm.cb1[i] = A.b1[i / N1][i % N1];
  for (int i = tid; i < 768; i += 512) {
    int r = i >> 6, w = i & 63;
    const float* W = (r < 3) ? A.gW + r * 128 : (r < 6) ? A.aW + (r - 3) * 128 : A.uW + (r - 6) * 128;
    ((uint32_t*)sm.hwq)[i] = pk2(W[2 * w], W[2 * w + 1]);
  }
  if (tid < 12) sm.hb[tid] = (tid < 3) ? A.gb[tid] : (tid < 6) ? A.ab[tid - 3] : A.ub[tid - 6];
  {
    uint32_t* zz = (uint32_t*)sm.zb;
    for (int i = tid; i < (2 * QG + Q0 + Q1N + Q2N) * 4; i += 512) zz[i] = 0u;
  }

  // register-resident weights (constant indexing only — never runtime-indexed)
  uint4 gwr[16];   // gate quads 26..33 for rows tid, tid+512
#pragma unroll
  for (int q = 0; q < 8; ++q) {
    gwr[q]     = A.wsG[(26 + q) * NRG + tid];
    gwr[8 + q] = A.wsG[(26 + q) * NRG + 512 + tid];
  }
  uint4 l2r[23];   // l2 row tid, all 23 quads
#pragma unroll
  for (int q = 0; q < Q2N; ++q) l2r[q] = A.wsL2[q * NR2 + tid];

  const float cbr = A.b2[tid >> 7][tid & 127];
  const float bgA = A.bih[tid] + A.bhh[tid];
  const float bgB = A.bih[tid + 512] + A.bhh[tid + 512];
  float c_r = 0.f;
  __syncthreads();

  // x(0) into zb[0]
  if (tid < 16) st16(sm.zb[0], tid, f16b(tid < DIN ? xb[tid] : 0.f));
  __syncthreads();

  // prologue: gates partial for t=0 (quads 0..17; h regions are zero)
  float accA = bgA, accB = bgB;
#pragma unroll 6
  for (int q = 0; q < 18; ++q) {
    uint4 z = sm.zb[0][q];
    accA = dot8f(A.wsG[q * NRG + tid], z, accA);
    accB = dot8f(A.wsG[q * NRG + 512 + tid], z, accB);
  }

  for (int t = 0; t < T_; ++t) {
    const int cur = t & 1, nxt = cur ^ 1;

    // ---- P1: gates final (quads 18..25 streamed, 26..33 from regs) ----
#pragma unroll 4
    for (int q = 0; q < 8; ++q) {
      uint4 z = sm.zb[cur][18 + q];
      accA = dot8f(A.wsG[(18 + q) * NRG + tid], z, accA);
      accB = dot8f(A.wsG[(18 + q) * NRG + 512 + tid], z, accB);
    }
#pragma unroll
    for (int q = 0; q < 8; ++q) {
      uint4 z = sm.zb[cur][26 + q];
      accA = dot8f(gwr[q], z, accA);
      accB = dot8f(gwr[8 + q], z, accB);
    }
    sm.garr[tid] = accA;
    sm.garr[512 + tid] = accB;
    __syncthreads();

    // ---- P2: LSTM (threads 0..255) + heads for t-1 (threads 256..267) ----
    if (tid < 256) {
      float gi = sm.garr[tid], gf = sm.garr[256 + tid];
      float gg = sm.garr[512 + tid], go = sm.garr[768 + tid];
      float cn = sigf(gf) * c_r + sigf(gi) * tanhf(gg);
      c_r = cn;
      float h = sigf(go) * tanhf(cn);
      unsigned short hb16 = f16b(h);
      if (tid < N0)            st16(sm.z0, 16 + tid, hb16);
      else if (tid < 128)      st16(sm.z1, tid - N0, hb16);
      else                     st16(sm.z2, tid - 128, hb16);
    } else if (tid < 268 && t > 0) {
      int r = tid - 256;
      float a = sm.hb[r];
#pragma unroll
      for (int q = 0; q < 16; ++q) a = dot8f(sm.hwq[r][q], sm.zb[cur][18 + q], a);
      size_t base = ((size_t)b * T_ + (t - 1)) * 6;
      if (r < 6) A.out[base + r] = a;
      else {
        float sp = (a > 0.f) ? (a + log1pf(expf(-a))) : log1pf(expf(a));
        A.out[UNC_OFF + base + (r - 6)] = sp;
      }
    }
    __syncthreads();

    // ---- P3: l0 fused matvec+combine (77 threads) ----
    if (tid < N0) {
      float a0 = sm.cb0[tid], a1 = sm.cb0[N0 + tid];
      float a2 = sm.cb0[2 * N0 + tid], a3 = sm.cb0[3 * N0 + tid];
#pragma unroll 4
      for (int q = 0; q < Q0; ++q) {
        uint4 z = sm.z0[q];
        a0 = dot8f(sm.l0w[q * NR0 + tid], z, a0);
        a1 = dot8f(sm.l0w[q * NR0 + N0 + tid], z, a1);
        a2 = dot8f(sm.l0w[q * NR0 + 2 * N0 + tid], z, a2);
        a3 = dot8f(sm.l0w[q * NR0 + 3 * N0 + tid], z, a3);
      }
      float ti = sigf(a2 + a3);
      float v = tanhf(a0) * (1.f - ti) + ti * tanhf(a1);
      unsigned short v16 = f16b(v);
      st16(sm.z1, 64 + tid, v16);
      st16(sm.zb[nxt], 16 + tid, v16);
    }
    __syncthreads();

    // ---- P4: l1 fused (51 threads) + x(t+1) prefetch (threads 64..79) ----
    if (tid < N1) {
      float a0 = sm.cb1[tid], a1 = sm.cb1[N1 + tid];
      float a2 = sm.cb1[2 * N1 + tid], a3 = sm.cb1[3 * N1 + tid];
#pragma unroll 6
      for (int q = 0; q < Q1N; ++q) {
        uint4 z = sm.z1[q];
        a0 = dot8f(sm.l1w[q * NR1 + tid], z, a0);
        a1 = dot8f(sm.l1w[q * NR1 + N1 + tid], z, a1);
        a2 = dot8f(sm.l1w[q * NR1 + 2 * N1 + tid], z, a2);
        a3 = dot8f(sm.l1w[q * NR1 + 3 * N1 + tid], z, a3);
      }
      float ti = sigf(a2 + a3);
      float v = tanhf(a0) * (1.f - ti) + ti * tanhf(a1);
      unsigned short v16 = f16b(v);
      st16(sm.z2, 128 + tid, v16);
      st16(sm.zb[nxt], 93 + tid, v16);
    } else if (tid >= 64 && tid < 80) {
      int i = tid - 64;
      float v = (t + 1 < T_ && i < DIN) ? xb[(size_t)(t + 1) * DIN + i] : 0.f;
      unsigned short v16 = f16b(v);
      st16(sm.zb[nxt], i, v16);
      st16(sm.z0, i, v16);
    }
    __syncthreads();

    // ---- P5: mega-stream: gates partial (t+1, quads 0..17) + l2 (regs) ----
    accA = bgA; accB = bgB;
#pragma unroll 6
    for (int q = 0; q < 18; ++q) {
      uint4 z = sm.zb[nxt][q];
      accA = dot8f(A.wsG[q * NRG + tid], z, accA);
      accB = dot8f(A.wsG[q * NRG + 512 + tid], z, accB);
    }
    {
      float a = cbr;
#pragma unroll
      for (int q = 0; q < Q2N; ++q) a = dot8f(l2r[q], sm.z2[q], a);
      sm.ffb[tid] = (tid < 256) ? tanhf(a) : a;
    }
    __syncthreads();

    // ---- P6: l2 combine (128 threads) ----
    if (tid < 128) {
      float ti = sigf(sm.ffb[256 + tid] + sm.ffb[384 + tid]);
      float v = sm.ffb[tid] * (1.f - ti) + ti * sm.ffb[128 + tid];
      st16(sm.zb[nxt], 144 + tid, f16b(v));
    }
    __syncthreads();
  }

  // ---- tail: heads for t = T_-1 (l2o in zb[0]) ----
  if (tid >= 256 && tid < 268) {
    int r = tid - 256;
    float a = sm.hb[r];
#pragma unroll
    for (int q = 0; q < 16; ++q) a = dot8f(sm.hwq[r][q], sm.zb[0][18 + q], a);
    size_t base = ((size_t)b * T_ + (T_ - 1)) * 6;
    if (r < 6) A.out[base + r] = a;
    else {
      float sp = (a > 0.f) ? (a + log1pf(expf(-a))) : log1pf(expf(a));
      A.out[UNC_OFF + base + (r - 6)] = sp;
    }
  }
}

// ================= fallback: direct f32 kernel (no workspace) =================

struct SMF {
  float xt[16];
  float lstm_h[HS];
  float hprev[HS];
  float garr[4 * HS];
  float ffb[4][128];
  float cb0[NR0];
  float cb1[NR1];
  float cb2[NR2];
  float hw[12][132];
  float hb[12];
};

__global__ __launch_bounds__(512, 2) void rnn_fallback(Args A) {
  extern __shared__ char smraw[];
  SMF& sm = *(SMF*)smraw;
  const int tid = threadIdx.x;
  const int b = blockIdx.x;

  for (int i = tid; i < NR0; i += 512) sm.cb0[i] = A.b0[i / N0][i % N0];
  for (int i = tid; i < NR1; i += 512) sm.cb1[i] = A.b1[i / N1][i % N1];
  for (int i = tid; i < NR2; i += 512) sm.cb2[i] = A.b2[i / N2][i % N2];
  for (int i = tid; i < 12 * 128; i += 512) {
    int r = i >> 7, k = i & 127;
    sm.hw[r][k] = (r < 3) ? A.gW[r * 128 + k]
                : (r < 6) ? A.aW[(r - 3) * 128 + k]
                          : A.uW[(r - 6) * 128 + k];
  }
  if (tid < 12) sm.hb[tid] = (tid < 3) ? A.gb[tid] : (tid < 6) ? A.ab[tid - 3] : A.ub[tid - 6];
  for (int i = tid; i < HS; i += 512) sm.hprev[i] = 0.f;
  float bga = A.bih[tid] + A.bhh[tid];
  float bgb = A.bih[tid + 512] + A.bhh[tid + 512];
  float c_r = 0.f;
  __syncthreads();

  const float* xb = A.x + (size_t)b * T_ * DIN;
  const size_t UNC_OFF = (size_t)B_ * T_ * 6;

  for (int t = 0; t < T_; ++t) {
    const float* xp = xb + (size_t)t * DIN;
    if (tid < DIN) sm.xt[tid] = xp[tid];
    __syncthreads();

    float aa = bga, ab = bgb;
    for (int k = 0; k < DIN; ++k) {
      float xv = sm.xt[k];
      aa += A.Wih[tid * DIN + k] * xv;
      ab += A.Wih[(tid + 512) * DIN + k] * xv;
    }
    for (int k = 0; k < HS; ++k) {
      float hv = sm.hprev[k];
      aa += A.Whh[tid * HS + k] * hv;
      ab += A.Whh[(tid + 512) * HS + k] * hv;
    }
    sm.garr[tid] = aa;
    sm.garr[tid + 512] = ab;
    __syncthreads();

    if (tid < HS) {
      float gi = sm.garr[tid], gf = sm.garr[HS + tid];
      float gg = sm.garr[2 * HS + tid], go = sm.garr[3 * HS + tid];
      float cn = sigf(gf) * c_r + sigf(gi) * tanhf(gg);
      c_r = cn;
      sm.lstm_h[tid] = sigf(go) * tanhf(cn);
    }
    __syncthreads();

    if (tid < NR0) {
      int mat = tid / N0, o = tid % N0;
      const float* W = A.W0[mat];
      const float* m = A.m0;
      const int Kl = DIN + N0;
      float acc = sm.cb0[tid];
      for (int k = 0; k < DIN; ++k) {
        float w = W[o * Kl + k];
        if (mat < 2) w *= m[o * Kl + k];
        acc += w * sm.xt[k];
      }
      for (int k = DIN; k < Kl; ++k) acc += W[o * Kl + k] * sm.lstm_h[k - DIN];
      sm.ffb[mat][o] = (mat < 2) ? tanhf(acc) : acc;
    }
    __syncthreads();
    if (tid < N0) {
      float ti = sigf(sm.ffb[2][tid] + sm.ffb[3][tid]);
      sm.hprev[tid] = sm.ffb[0][tid] * (1.f - ti) + ti * sm.ffb[1][tid];
    }
    __syncthreads();

    if (tid < NR1) {
      int mat = tid / N1, o = tid % N1;
      const float* W = A.W1[mat];
      const float* m = A.m1;
      const int Kl = N0 + N1;
      float acc = sm.cb1[tid];
      for (int k = 0; k < N0; ++k) {
        float w = W[o * Kl + k];
        if (mat < 2) w *= m[o * Kl + k];
        acc += w * sm.hprev[k];
      }
      for (int k = N0; k < Kl; ++k) acc += W[o * Kl + k] * sm.lstm_h[k];
      sm.ffb[mat][o] = (mat < 2) ? tanhf(acc) : acc;
    }
    __syncthreads();
    if (tid < N1) {
      float ti = sigf(sm.ffb[2][tid] + sm.ffb[3][tid]);
      sm.hprev[N0 + tid] = sm.ffb[0][tid] * (1.f - ti) + ti * sm.ffb[1][tid];
    }
    __syncthreads();

    {
      int mat = tid >> 7, o = tid & 127;
      const float* W = A.W2[mat];
      const float* m = A.m2;
      const int Kl = N1 + N2;
      float acc = sm.cb2[tid];
      for (int k = 0; k < N1; ++k) {
        float w = W[o * Kl + k];
        if (mat < 2) w *= m[o * Kl + k];
        acc += w * sm.hprev[N0 + k];
      }
      for (int k = N1; k < Kl; ++k) acc += W[o * Kl + k] * sm.lstm_h[N0 + k];
      sm.ffb[mat][o] = (mat < 2) ? tanhf(acc) : acc;
    }
    __syncthreads();
    if (tid < N2) {
      float ti = sigf(sm.ffb[2][tid] + sm.ffb[3][tid]);
      sm.hprev[N0 + N1 + tid] = sm.ffb[0][tid] * (1.f - ti) + ti * sm.ffb[1][tid];
    }
    __syncthreads();

    if (tid >= 256 && tid < 268) {
      int r = tid - 256;
      const float* mo = &sm.hprev[N0 + N1];
      float acc = sm.hb[r];
      for (int k = 0; k < 128; ++k) acc += sm.hw[r][k] * mo[k];
      size_t base = ((size_t)b * T_ + t) * 6;
      if (r < 6) A.out[base + r] = acc;
      else {
        float sp = (acc > 0.f) ? (acc + log1pf(expf(-acc))) : log1pf(expf(acc));
        A.out[UNC_OFF + base + (r - 6)] = sp;
      }
    }
    __syncthreads();
  }
}

// ---------------- launcher ----------------

extern "C" void kernel_launch(void* const* d_in, const int* in_sizes, int n_in,
                              void* d_out, int out_size, void* d_ws, size_t ws_size,
                              hipStream_t stream) {
  Args A;
  A.x   = (const float*)d_in[0];
  A.Wih = (const float*)d_in[1];
  A.Whh = (const float*)d_in[2];
  A.bih = (const float*)d_in[3];
  A.bhh = (const float*)d_in[4];
  const float** Wl[3] = {A.W0, A.W1, A.W2};
  const float** bl[3] = {A.b0, A.b1, A.b2};
  const float* ml[3];
  for (int l = 0; l < 3; ++l) {
    int base = 5 + l * 9;
    for (int nm = 0; nm < 4; ++nm) {
      Wl[l][nm] = (const float*)d_in[base + 2 * nm];
      bl[l][nm] = (const float*)d_in[base + 2 * nm + 1];
    }
    ml[l] = (const float*)d_in[base + 8];
  }
  A.m0 = ml[0]; A.m1 = ml[1]; A.m2 = ml[2];
  A.gW = (const float*)d_in[32];
  A.gb = (const float*)d_in[33];
  A.aW = (const float*)d_in[34];
  A.ab = (const float*)d_in[35];
  A.uW = (const float*)d_in[36];
  A.ub = (const float*)d_in[37];
  A.out = (float*)d_out;

  const size_t szG  = (size_t)QG * NRG * 16;    // 557056
  const size_t szL0 = (size_t)Q0 * NR0 * 16;    // 59136
  const size_t szL1 = (size_t)Q1N * NR1 * 16;   // 58752
  const size_t szL2 = (size_t)Q2N * NR2 * 16;   // 188416
  const size_t offG = 0, offL0 = szG, offL1 = offL0 + szL0, offL2 = offL1 + szL1;
  const size_t need = offL2 + szL2;             // 863360

  char* ws = (char*)d_ws;
  A.wsG  = (const uint4*)(ws + offG);
  A.wsL0 = (const uint4*)(ws + offL0);
  A.wsL1 = (const uint4*)(ws + offL1);
  A.wsL2 = (const uint4*)(ws + offL2);

  if (ws_size >= need) {
    int n;
    n = K2G * NRG;
    prep_gates2<<<(n + 255) / 256, 256, 0, stream>>>(A.Wih, A.Whh, (uint32_t*)(ws + offG));
    n = NR0 * 48;
    prep_cfc2<<<(n + 255) / 256, 256, 0, stream>>>(A.W0[0], A.W0[1], A.W0[2], A.W0[3], A.m0,
                                                   N0, DIN + N0, NR0, 48,
                                                   13, 0, 16, 77, 13,
                                                   (uint32_t*)(ws + offL0));
    n = NR1 * 72;
    prep_cfc2<<<(n + 255) / 256, 256, 0, stream>>>(A.W1[0], A.W1[1], A.W1[2], A.W1[3], A.m1,
                                                   N1, N0 + N1, NR1, 72,
                                                   51, 77, 64, 77, 0,
                                                   (uint32_t*)(ws + offL1));
    n = NR2 * 92;
    prep_cfc2<<<(n + 255) / 256, 256, 0, stream>>>(A.W2[0], A.W2[1], A.W2[2], A.W2[3], A.m2,
                                                   N2, N1 + N2, NR2, 92,
                                                   128, 51, 128, 51, 0,
                                                   (uint32_t*)(ws + offL2));
    hipFuncSetAttribute(reinterpret_cast<const void*>(&rnn_pipe),
                        hipFuncAttributeMaxDynamicSharedMemorySize, (int)sizeof(SMP));
    rnn_pipe<<<B_, 512, sizeof(SMP), stream>>>(A);
  } else {
    hipFuncSetAttribute(reinterpret_cast<const void*>(&rnn_fallback),
                        hipFuncAttributeMaxDynamicSharedMemorySize, (int)sizeof(SMF));
    rnn_fallback<<<B_, 512, sizeof(SMF), stream>>>(A);
  }
}

// Round 5
// 7995.116 us; speedup vs baseline: 6.3735x; 1.5148x over previous
//
#include <hip/hip_runtime.h>
#include <cstdint>

#define B_  128
#define T_  1024
#define DIN 13
#define HS  256
#define N0  77
#define N1  51
#define N2  128

// zg layout (f16 elems, 272 = 34 quads):
//   e0..12 x (13..15 pad) | e16..143 l2o | e144..194 l1o | e195..271 l0o
// quads: {0,1}=x  {2..17}=l2o  {18..24}=l1o(+l0o[0..4])  {25..33}=l0o
#define QG   34
#define NRG  1024
// z0 (l0 in): e0..12 x | e13..89 h[0:77] | pad..95  -> 12 quads, 308 rows
#define Q0   12
#define NR0  308
// z1 (l1 in): e0..50 h[77:128] | e51..127 l0o  -> 16 quads, 204 rows
#define Q1   16
#define NR1  204
// z2 (l2 in): e0..50 l1o | 51..55 pad | e56..183 h[128:256] -> 23 quads, 512 rows
#define Q2   23
#define NR2  512

#define UA   63          // A's l2 units 0..62
#define UB   65          // B's l2 units 63..127
#define RA   (4*UA)      // 252
#define RB   (4*UB)      // 260

// exchange (per b, stride 448 int/float):
#define EXSTRIDE 448
#define X1O   0          // [0..50]=h[77:128], [51..127]=l0o
#define X2HO  128        // h2 = h[128:256]
#define X2LO  256        // l1o (51)
#define X3AO  307        // l2o[0:63]
#define X3BO  370        // l2o[63:128] (65)
#define FLGO  440        // +0 f1, +1 f2a, +2 f2b, +3 f3a, +4 f3b

typedef _Float16 h2_t __attribute__((ext_vector_type(2)));

static __device__ __forceinline__ uint32_t pk2(float a, float b) {
  h2_t v; v.x = (_Float16)a; v.y = (_Float16)b;
  return __builtin_bit_cast(uint32_t, v);
}
static __device__ __forceinline__ unsigned short f16b(float v) {
  return __builtin_bit_cast(unsigned short, (_Float16)v);
}
static __device__ __forceinline__ void st16(void* base, int idx, unsigned short v) {
  ((unsigned short*)base)[idx] = v;
}
static __device__ __forceinline__ float dot2f(uint32_t w, uint32_t z, float acc) {
#if __has_builtin(__builtin_amdgcn_fdot2)
  return __builtin_amdgcn_fdot2(__builtin_bit_cast(h2_t, w), __builtin_bit_cast(h2_t, z), acc, false);
#else
  h2_t a = __builtin_bit_cast(h2_t, w), b = __builtin_bit_cast(h2_t, z);
  return acc + (float)a.x * (float)b.x + (float)a.y * (float)b.y;
#endif
}
static __device__ __forceinline__ float dot8f(uint4 w, uint4 z, float acc) {
  acc = dot2f(w.x, z.x, acc);
  acc = dot2f(w.y, z.y, acc);
  acc = dot2f(w.z, z.z, acc);
  acc = dot2f(w.w, z.w, acc);
  return acc;
}
static __device__ __forceinline__ float sigf(float x) { return 1.f / (1.f + expf(-x)); }

// fence-free exchange primitives: relaxed device-scope atomics (coherent at the
// coherence point, bypass stale L1/L2 WITHOUT invalidating them — round-2's
// acquire/release fences invalidated per-XCD L2 and caused a 360 MB/dispatch
// HBM refetch storm).
static __device__ __forceinline__ void axstore(int* p, float v) {
  __hip_atomic_store(p, __builtin_bit_cast(int, v), __ATOMIC_RELAXED, __HIP_MEMORY_SCOPE_AGENT);
}
static __device__ __forceinline__ void axstorei(int* p, int v) {
  __hip_atomic_store(p, v, __ATOMIC_RELAXED, __HIP_MEMORY_SCOPE_AGENT);
}
static __device__ __forceinline__ float axload(const int* p) {
  return __builtin_bit_cast(float, __hip_atomic_load((int*)p, __ATOMIC_RELAXED, __HIP_MEMORY_SCOPE_AGENT));
}
static __device__ __forceinline__ void vmw() {
  asm volatile("s_waitcnt vmcnt(0)" ::: "memory");
}
static __device__ __forceinline__ void flag_wait(const int* p, int v) {
  while (__hip_atomic_load((int*)p, __ATOMIC_RELAXED, __HIP_MEMORY_SCOPE_AGENT) < v)
    __builtin_amdgcn_s_sleep(2);
}

// ---------------- prep kernels ----------------

__global__ void prep_gates3(const float* __restrict__ Wih, const float* __restrict__ Whh,
                            uint32_t* __restrict__ out) {
  int id = blockIdx.x * blockDim.x + threadIdx.x;
  if (id >= 136 * NRG) return;
  int k2 = id >> 10, row = id & (NRG - 1);
  float v[2];
#pragma unroll
  for (int j = 0; j < 2; ++j) {
    int e = 2 * k2 + j;
    float val = 0.f;
    if (e < 13) val = Wih[row * DIN + e];
    else if (e >= 16 && e < 144) val = Whh[row * HS + 128 + (e - 16)];
    else if (e >= 144 && e < 195) val = Whh[row * HS + 77 + (e - 144)];
    else if (e >= 195 && e < 272) val = Whh[row * HS + (e - 195)];
    v[j] = val;
  }
  out[((k2 >> 2) * NRG + row) * 4 + (k2 & 3)] = pk2(v[0], v[1]);
}

__global__ void prep_cfc2(const float* __restrict__ Wf1, const float* __restrict__ Wf2,
                          const float* __restrict__ Wta, const float* __restrict__ Wtb,
                          const float* __restrict__ mask,
                          int nh, int K, int NR, int K2,
                          int p0n, int p0c, int p1s, int p1n, int p1c,
                          uint32_t* __restrict__ out) {
  int id = blockIdx.x * blockDim.x + threadIdx.x;
  if (id >= NR * K2) return;
  int k2 = id / NR, r = id % NR;
  int mat = r / nh, o = r % nh;
  const float* W = (mat == 0) ? Wf1 : (mat == 1) ? Wf2 : (mat == 2) ? Wta : Wtb;
  float v[2];
#pragma unroll
  for (int j = 0; j < 2; ++j) {
    int e = 2 * k2 + j;
    int col = -1;
    if (e < p0n) col = p0c + e;
    else if (e >= p1s && e < p1s + p1n) col = p1c + (e - p1s);
    float val = 0.f;
    if (col >= 0) {
      val = W[o * K + col];
      if (mat < 2) val *= mask[o * K + col];
    }
    v[j] = val;
  }
  out[((k2 >> 2) * NR + r) * 4 + (k2 & 3)] = pk2(v[0], v[1]);
}

// ---------------- shared structs ----------------

struct SMA {
  uint4 l0w[Q0 * NR0];   // 59136
  uint4 l2w[Q2 * RA];    // 92736
  uint4 zb[2][QG];       // 1088
  uint4 z0[Q0];          // 192
  uint4 z2[Q2];          // 368
  float garr[512];       // 2048
  float ffb[NR0];        // 1232
  float cb0[NR0];        // 1232
  float cb2[RA];         // 1008
};
struct SMB {
  uint4 l1w[Q1 * NR1];   // 52224
  uint4 l2w[Q2 * RB];    // 95680
  uint4 zb[2][QG];       // 1088
  uint4 z1[Q1];          // 256
  uint4 z2[Q2];          // 368
  float garr[512];       // 2048
  float ffb[RB];         // 1040
  float cb1[NR1];        // 816
  float cb2[RB];         // 1040
  uint4 hwq[12][16];     // 3072
  float hb[12];          // 48
};
static_assert(sizeof(SMA) <= 163840, "SMA too big");
static_assert(sizeof(SMB) <= 163840, "SMB too big");

struct PArgs {
  const float* x;
  const float* bih; const float* bhh;
  const float* b0[4]; const float* b1[4]; const float* b2[4];
  const float* gW; const float* gb; const float* aW; const float* ab;
  const float* uW; const float* ub;
  const uint4* wsG; const uint4* wsL0; const uint4* wsL1; const uint4* wsL2;
  int* ex;
  float* out;
};

__global__ __launch_bounds__(512, 2) void rnn_coop(PArgs P) {
  extern __shared__ char smraw[];
  const int tid = threadIdx.x;
  const bool isA = (blockIdx.x < B_);
  const int b = blockIdx.x & (B_ - 1);
  int* EX = P.ex + b * EXSTRIDE;
  int* FLG = EX + FLGO;
  const float* xb = P.x + (size_t)b * T_ * DIN;
  const size_t UNC_OFF = (size_t)B_ * T_ * 6;

  if (isA) {
    SMA& sm = *(SMA*)smraw;
    for (int i = tid; i < Q0 * NR0; i += 512) sm.l0w[i] = P.wsL0[i];
    for (int i = tid; i < Q2 * RA; i += 512) {
      int q = i / RA, r = i % RA;
      sm.l2w[i] = P.wsL2[q * NR2 + (r / UA) * 128 + (r % UA)];
    }
    for (int i = tid; i < NR0; i += 512) sm.cb0[i] = P.b0[i / N0][i % N0];
    for (int i = tid; i < RA; i += 512) sm.cb2[i] = P.b2[i / UA][i % UA];
    {
      uint32_t* zz = (uint32_t*)sm.zb;
      for (int i = tid; i < (2 * QG + Q0 + Q2) * 4; i += 512) zz[i] = 0u;
    }
    const int grow = ((tid >> 7) << 8) | (tid & 127);   // units 0..127
    const float bg = P.bih[grow] + P.bhh[grow];
    float c_r = 0.f;
    __syncthreads();
    if (tid < 13) {
      unsigned short v = f16b(xb[tid]);
      st16(sm.zb[0], tid, v);
      st16(sm.z0, tid, v);
    }
    __syncthreads();
    float acc = bg;
    acc = dot8f(P.wsG[0 * NRG + grow], sm.zb[0][0], acc);
    acc = dot8f(P.wsG[1 * NRG + grow], sm.zb[0][1], acc);
    uint4* zbc = sm.zb[0];
    uint4* zbn = sm.zb[1];

    for (int t = 0; t < T_; ++t) {
      // F: finish gates quads 2..17 (l2o region of current buffer)
#pragma unroll 8
      for (int q = 2; q < 18; ++q)
        acc = dot8f(P.wsG[q * NRG + grow], zbc[q], acc);
      sm.garr[tid] = acc;
      __syncthreads();
      // LSTM units 0..127
      if (tid < 128) {
        float gi = sm.garr[tid], gf = sm.garr[128 + tid];
        float gg = sm.garr[256 + tid], go = sm.garr[384 + tid];
        float cn = sigf(gf) * c_r + sigf(gi) * tanhf(gg);
        c_r = cn;
        float h = sigf(go) * tanhf(cn);
        if (tid < N0) st16(sm.z0, 13 + tid, f16b(h));
        else          axstore(EX + X1O + (tid - N0), h);   // h[77:128]
      }
      __syncthreads();
      // l0 matvec + x(t+1) prefetch into zbn
      if (tid < NR0) {
        float a = sm.cb0[tid];
#pragma unroll
        for (int q = 0; q < Q0; ++q) a = dot8f(sm.l0w[q * NR0 + tid], sm.z0[q], a);
        sm.ffb[tid] = (tid < 2 * N0) ? tanhf(a) : a;
      } else if (tid >= 320 && tid < 336) {
        int i = tid - 320;
        if (i < 13) {
          float xv = (t + 1 < T_) ? xb[(size_t)(t + 1) * DIN + i] : 0.f;
          st16(zbn, i, f16b(xv));
        }
      }
      __syncthreads();
      // combine l0 -> l0o; x copy zbn->z0
      if (tid < N0) {
        float ti = sigf(sm.ffb[2 * N0 + tid] + sm.ffb[3 * N0 + tid]);
        float v = sm.ffb[tid] * (1.f - ti) + ti * sm.ffb[N0 + tid];
        st16(zbn, 195 + tid, f16b(v));
        axstore(EX + X1O + 51 + tid, v);
      } else if (tid >= 96 && tid < 112) {
        int i = tid - 96;
        if (i < 13) st16(sm.z0, i, ((unsigned short*)zbn)[i]);
      }
      vmw();
      __syncthreads();
      if (tid == 0) axstorei(FLG + 0, t + 1);            // f1: {h[77:128], l0o}
      // partial gates(t+1): x + l0o quads
      acc = bg;
      acc = dot8f(P.wsG[0 * NRG + grow], zbn[0], acc);
      acc = dot8f(P.wsG[1 * NRG + grow], zbn[1], acc);
#pragma unroll
      for (int q = 25; q < 34; ++q)
        acc = dot8f(P.wsG[q * NRG + grow], zbn[q], acc);
      // h2 from B
      if (tid == 0) flag_wait(FLG + 1, t + 1);           // f2a
      __syncthreads();
      if (tid < 128) st16(sm.z2, 56 + tid, f16b(axload(EX + X2HO + tid)));
      __syncthreads();
      // l2A partial (h2 quads 7..22)
      float fl2 = 0.f;
      if (tid < RA) {
        fl2 = sm.cb2[tid];
#pragma unroll
        for (int q = 7; q < Q2; ++q) fl2 = dot8f(sm.l2w[q * RA + tid], sm.z2[q], fl2);
      }
      // l1o from B
      if (tid == 0) flag_wait(FLG + 2, t + 1);           // f2b
      __syncthreads();
      if (tid < N1) {
        unsigned short v16 = f16b(axload(EX + X2LO + tid));
        st16(sm.z2, tid, v16);
        st16(zbn, 144 + tid, v16);
      }
      __syncthreads();
      // partial gates l1o quads + l2A finish
#pragma unroll
      for (int q = 18; q < 25; ++q)
        acc = dot8f(P.wsG[q * NRG + grow], zbn[q], acc);
      if (tid < RA) {
#pragma unroll
        for (int q = 0; q < 7; ++q) fl2 = dot8f(sm.l2w[q * RA + tid], sm.z2[q], fl2);
        sm.ffb[tid] = (tid < 2 * UA) ? tanhf(fl2) : fl2;
      }
      __syncthreads();
      // combine l2A
      if (tid < UA) {
        float ti = sigf(sm.ffb[2 * UA + tid] + sm.ffb[3 * UA + tid]);
        float v = sm.ffb[tid] * (1.f - ti) + ti * sm.ffb[UA + tid];
        st16(zbn, 16 + tid, f16b(v));
        axstore(EX + X3AO + tid, v);
      }
      vmw();
      __syncthreads();
      if (tid == 0) {
        axstorei(FLG + 3, t + 1);                        // f3a
        flag_wait(FLG + 4, t + 1);                       // f3b
      }
      __syncthreads();
      if (tid < UB) st16(zbn, 16 + UA + tid, f16b(axload(EX + X3BO + tid)));
      __syncthreads();
      uint4* tmp = zbc; zbc = zbn; zbn = tmp;
    }
  } else {
    // ======================= role B =======================
    SMB& sm = *(SMB*)smraw;
    for (int i = tid; i < Q1 * NR1; i += 512) sm.l1w[i] = P.wsL1[i];
    for (int i = tid; i < Q2 * RB; i += 512) {
      int q = i / RB, r = i % RB;
      sm.l2w[i] = P.wsL2[q * NR2 + (r / UB) * 128 + UA + (r % UB)];
    }
    for (int i = tid; i < NR1; i += 512) sm.cb1[i] = P.b1[i / N1][i % N1];
    for (int i = tid; i < RB; i += 512) sm.cb2[i] = P.b2[i / UB][UA + (i % UB)];
    for (int i = tid; i < 768; i += 512) {
      int r = i >> 6, w = i & 63;
      const float* W = (r < 3) ? P.gW + r * 128 : (r < 6) ? P.aW + (r - 3) * 128 : P.uW + (r - 6) * 128;
      ((uint32_t*)sm.hwq)[i] = pk2(W[2 * w], W[2 * w + 1]);
    }
    if (tid < 12) sm.hb[tid] = (tid < 3) ? P.gb[tid] : (tid < 6) ? P.ab[tid - 3] : P.ub[tid - 6];
    {
      uint32_t* zz = (uint32_t*)sm.zb;
      for (int i = tid; i < (2 * QG + Q1 + Q2) * 4; i += 512) zz[i] = 0u;
    }
    const int grow = ((tid >> 7) << 8) | 128 | (tid & 127);   // units 128..255
    const float bg = P.bih[grow] + P.bhh[grow];
    float c_r = 0.f;
    __syncthreads();
    if (tid < 13) st16(sm.zb[0], tid, f16b(xb[tid]));
    __syncthreads();
    float acc = bg;
    acc = dot8f(P.wsG[0 * NRG + grow], sm.zb[0][0], acc);
    acc = dot8f(P.wsG[1 * NRG + grow], sm.zb[0][1], acc);
    uint4* zbc = sm.zb[0];
    uint4* zbn = sm.zb[1];

    for (int t = 0; t < T_; ++t) {
      // F: finish gates quads 2..17
#pragma unroll 8
      for (int q = 2; q < 18; ++q)
        acc = dot8f(P.wsG[q * NRG + grow], zbc[q], acc);
      sm.garr[tid] = acc;
      __syncthreads();
      // LSTM units 128..255 + heads(t-1) + x(t+1) prefetch
      if (tid < 128) {
        float gi = sm.garr[tid], gf = sm.garr[128 + tid];
        float gg = sm.garr[256 + tid], go = sm.garr[384 + tid];
        float cn = sigf(gf) * c_r + sigf(gi) * tanhf(gg);
        c_r = cn;
        float h = sigf(go) * tanhf(cn);
        st16(sm.z2, 56 + tid, f16b(h));
        axstore(EX + X2HO + tid, h);
      } else if (tid < 140) {
        if (t > 0) {
          int r = tid - 128;
          float a = sm.hb[r];
#pragma unroll
          for (int q = 0; q < 16; ++q) a = dot8f(sm.hwq[r][q], zbc[2 + q], a);
          size_t base = ((size_t)b * T_ + (t - 1)) * 6;
          if (r < 6) P.out[base + r] = a;
          else {
            float sp = (a > 0.f) ? (a + log1pf(expf(-a))) : log1pf(expf(a));
            P.out[UNC_OFF + base + (r - 6)] = sp;
          }
        }
      } else if (tid >= 192 && tid < 208) {
        int i = tid - 192;
        if (i < 13) {
          float xv = (t + 1 < T_) ? xb[(size_t)(t + 1) * DIN + i] : 0.f;
          st16(zbn, i, f16b(xv));
        }
      }
      vmw();
      __syncthreads();
      if (tid == 0) axstorei(FLG + 1, t + 1);            // f2a: h2
      // l2B partial (h2 quads 7..22, local)
      float fl2 = 0.f;
      if (tid < RB) {
        fl2 = sm.cb2[tid];
#pragma unroll
        for (int q = 7; q < Q2; ++q) fl2 = dot8f(sm.l2w[q * RB + tid], sm.z2[q], fl2);
      }
      // {h[77:128], l0o} from A
      if (tid == 0) flag_wait(FLG + 0, t + 1);           // f1
      __syncthreads();
      if (tid < 128) {
        float v = axload(EX + X1O + tid);
        st16(sm.z1, tid, f16b(v));
        if (tid >= 51) st16(zbn, 195 + (tid - 51), f16b(v));   // l0o
      }
      __syncthreads();
      // partial gates(t+1): x + l0o quads
      acc = bg;
      acc = dot8f(P.wsG[0 * NRG + grow], zbn[0], acc);
      acc = dot8f(P.wsG[1 * NRG + grow], zbn[1], acc);
#pragma unroll
      for (int q = 25; q < 34; ++q)
        acc = dot8f(P.wsG[q * NRG + grow], zbn[q], acc);
      // l1 matvec
      if (tid < NR1) {
        float a = sm.cb1[tid];
#pragma unroll
        for (int q = 0; q < Q1; ++q) a = dot8f(sm.l1w[q * NR1 + tid], sm.z1[q], a);
        sm.ffb[tid] = (tid < 2 * N1) ? tanhf(a) : a;
      }
      __syncthreads();
      // combine l1 -> l1o
      if (tid < N1) {
        float ti = sigf(sm.ffb[2 * N1 + tid] + sm.ffb[3 * N1 + tid]);
        float v = sm.ffb[tid] * (1.f - ti) + ti * sm.ffb[N1 + tid];
        unsigned short v16 = f16b(v);
        st16(sm.z2, tid, v16);
        st16(zbn, 144 + tid, v16);
        axstore(EX + X2LO + tid, v);
      }
      vmw();
      __syncthreads();
      if (tid == 0) axstorei(FLG + 2, t + 1);            // f2b
      // partial gates l1o quads + l2B finish
#pragma unroll
      for (int q = 18; q < 25; ++q)
        acc = dot8f(P.wsG[q * NRG + grow], zbn[q], acc);
      if (tid < RB) {
#pragma unroll
        for (int q = 0; q < 7; ++q) fl2 = dot8f(sm.l2w[q * RB + tid], sm.z2[q], fl2);
        sm.ffb[tid] = (tid < 2 * UB) ? tanhf(fl2) : fl2;
      }
      __syncthreads();
      // combine l2B
      if (tid < UB) {
        float ti = sigf(sm.ffb[2 * UB + tid] + sm.ffb[3 * UB + tid]);
        float v = sm.ffb[tid] * (1.f - ti) + ti * sm.ffb[UB + tid];
        st16(zbn, 16 + UA + tid, f16b(v));
        axstore(EX + X3BO + tid, v);
      }
      vmw();
      __syncthreads();
      if (tid == 0) {
        axstorei(FLG + 4, t + 1);                        // f3b
        flag_wait(FLG + 3, t + 1);                       // f3a
      }
      __syncthreads();
      if (tid < UA) st16(zbn, 16 + tid, f16b(axload(EX + X3AO + tid)));
      __syncthreads();
      uint4* tmp = zbc; zbc = zbn; zbn = tmp;
    }
    // tail: heads for t = T_-1 (l2o now in zbc)
    if (tid >= 128 && tid < 140) {
      int r = tid - 128;
      float a = sm.hb[r];
#pragma unroll
      for (int q = 0; q < 16; ++q) a = dot8f(sm.hwq[r][q], zbc[2 + q], a);
      size_t base = ((size_t)b * T_ + (T_ - 1)) * 6;
      if (r < 6) P.out[base + r] = a;
      else {
        float sp = (a > 0.f) ? (a + log1pf(expf(-a))) : log1pf(expf(a));
        P.out[UNC_OFF + base + (r - 6)] = sp;
      }
    }
  }
}

// ================= fallback: direct f32 kernel (no workspace) =================

struct Args {
  const float* x;
  const float* Wih; const float* Whh; const float* bih; const float* bhh;
  const float* W0[4]; const float* b0[4]; const float* m0;
  const float* W1[4]; const float* b1[4]; const float* m1;
  const float* W2[4]; const float* b2[4]; const float* m2;
  const float* gW; const float* gb; const float* aW; const float* ab;
  const float* uW; const float* ub;
  float* out;
};

struct SMF {
  float xt[16];
  float lstm_h[HS];
  float hprev[HS];
  float garr[4 * HS];
  float ffb[4][128];
  float cb0[NR0];
  float cb1[NR1];
  float cb2[NR2];
  float hw[12][132];
  float hb[12];
};

__global__ __launch_bounds__(512, 2) void rnn_fallback(Args A) {
  extern __shared__ char smraw[];
  SMF& sm = *(SMF*)smraw;
  const int tid = threadIdx.x;
  const int b = blockIdx.x;

  for (int i = tid; i < NR0; i += 512) sm.cb0[i] = A.b0[i / N0][i % N0];
  for (int i = tid; i < NR1; i += 512) sm.cb1[i] = A.b1[i / N1][i % N1];
  for (int i = tid; i < NR2; i += 512) sm.cb2[i] = A.b2[i / N2][i % N2];
  for (int i = tid; i < 12 * 128; i += 512) {
    int r = i >> 7, k = i & 127;
    sm.hw[r][k] = (r < 3) ? A.gW[r * 128 + k]
                : (r < 6) ? A.aW[(r - 3) * 128 + k]
                          : A.uW[(r - 6) * 128 + k];
  }
  if (tid < 12) sm.hb[tid] = (tid < 3) ? A.gb[tid] : (tid < 6) ? A.ab[tid - 3] : A.ub[tid - 6];
  for (int i = tid; i < HS; i += 512) sm.hprev[i] = 0.f;
  float bga = A.bih[tid] + A.bhh[tid];
  float bgb = A.bih[tid + 512] + A.bhh[tid + 512];
  float c_r = 0.f;
  __syncthreads();

  const float* xb = A.x + (size_t)b * T_ * DIN;
  const size_t UNC_OFF = (size_t)B_ * T_ * 6;

  for (int t = 0; t < T_; ++t) {
    const float* xp = xb + (size_t)t * DIN;
    if (tid < DIN) sm.xt[tid] = xp[tid];
    __syncthreads();

    float aa = bga, ab = bgb;
    for (int k = 0; k < DIN; ++k) {
      float xv = sm.xt[k];
      aa += A.Wih[tid * DIN + k] * xv;
      ab += A.Wih[(tid + 512) * DIN + k] * xv;
    }
    for (int k = 0; k < HS; ++k) {
      float hv = sm.hprev[k];
      aa += A.Whh[tid * HS + k] * hv;
      ab += A.Whh[(tid + 512) * HS + k] * hv;
    }
    sm.garr[tid] = aa;
    sm.garr[tid + 512] = ab;
    __syncthreads();

    if (tid < HS) {
      float gi = sm.garr[tid], gf = sm.garr[HS + tid];
      float gg = sm.garr[2 * HS + tid], go = sm.garr[3 * HS + tid];
      float cn = sigf(gf) * c_r + sigf(gi) * tanhf(gg);
      c_r = cn;
      sm.lstm_h[tid] = sigf(go) * tanhf(cn);
    }
    __syncthreads();

    if (tid < NR0) {
      int mat = tid / N0, o = tid % N0;
      const float* W = A.W0[mat];
      const float* m = A.m0;
      const int Kl = DIN + N0;
      float acc = sm.cb0[tid];
      for (int k = 0; k < DIN; ++k) {
        float w = W[o * Kl + k];
        if (mat < 2) w *= m[o * Kl + k];
        acc += w * sm.xt[k];
      }
      for (int k = DIN; k < Kl; ++k) acc += W[o * Kl + k] * sm.lstm_h[k - DIN];
      sm.ffb[mat][o] = (mat < 2) ? tanhf(acc) : acc;
    }
    __syncthreads();
    if (tid < N0) {
      float ti = sigf(sm.ffb[2][tid] + sm.ffb[3][tid]);
      sm.hprev[tid] = sm.ffb[0][tid] * (1.f - ti) + ti * sm.ffb[1][tid];
    }
    __syncthreads();

    if (tid < NR1) {
      int mat = tid / N1, o = tid % N1;
      const float* W = A.W1[mat];
      const float* m = A.m1;
      const int Kl = N0 + N1;
      float acc = sm.cb1[tid];
      for (int k = 0; k < N0; ++k) {
        float w = W[o * Kl + k];
        if (mat < 2) w *= m[o * Kl + k];
        acc += w * sm.hprev[k];
      }
      for (int k = N0; k < Kl; ++k) acc += W[o * Kl + k] * sm.lstm_h[k];
      sm.ffb[mat][o] = (mat < 2) ? tanhf(acc) : acc;
    }
    __syncthreads();
    if (tid < N1) {
      float ti = sigf(sm.ffb[2][tid] + sm.ffb[3][tid]);
      sm.hprev[N0 + tid] = sm.ffb[0][tid] * (1.f - ti) + ti * sm.ffb[1][tid];
    }
    __syncthreads();

    {
      int mat = tid >> 7, o = tid & 127;
      const float* W = A.W2[mat];
      const float* m = A.m2;
      const int Kl = N1 + N2;
      float acc = sm.cb2[tid];
      for (int k = 0; k < N1; ++k) {
        float w = W[o * Kl + k];
        if (mat < 2) w *= m[o * Kl + k];
        acc += w * sm.hprev[N0 + k];
      }
      for (int k = N1; k < Kl; ++k) acc += W[o * Kl + k] * sm.lstm_h[N0 + k];
      sm.ffb[mat][o] = (mat < 2) ? tanhf(acc) : acc;
    }
    __syncthreads();
    if (tid < N2) {
      float ti = sigf(sm.ffb[2][tid] + sm.ffb[3][tid]);
      sm.hprev[N0 + N1 + tid] = sm.ffb[0][tid] * (1.f - ti) + ti * sm.ffb[1][tid];
    }
    __syncthreads();

    if (tid >= 256 && tid < 268) {
      int r = tid - 256;
      const float* mo = &sm.hprev[N0 + N1];
      float acc = sm.hb[r];
      for (int k = 0; k < 128; ++k) acc += sm.hw[r][k] * mo[k];
      size_t base = ((size_t)b * T_ + t) * 6;
      if (r < 6) A.out[base + r] = acc;
      else {
        float sp = (acc > 0.f) ? (acc + log1pf(expf(-acc))) : log1pf(expf(acc));
        A.out[UNC_OFF + base + (r - 6)] = sp;
      }
    }
    __syncthreads();
  }
}

// ---------------- launcher ----------------

extern "C" void kernel_launch(void* const* d_in, const int* in_sizes, int n_in,
                              void* d_out, int out_size, void* d_ws, size_t ws_size,
                              hipStream_t stream) {
  const float* x   = (const float*)d_in[0];
  const float* Wih = (const float*)d_in[1];
  const float* Whh = (const float*)d_in[2];
  const float* bih = (const float*)d_in[3];
  const float* bhh = (const float*)d_in[4];
  const float *W[3][4], *bb[3][4], *mk[3];
  for (int l = 0; l < 3; ++l) {
    int base = 5 + l * 9;
    for (int nm = 0; nm < 4; ++nm) {
      W[l][nm]  = (const float*)d_in[base + 2 * nm];
      bb[l][nm] = (const float*)d_in[base + 2 * nm + 1];
    }
    mk[l] = (const float*)d_in[base + 8];
  }
  const float* gW = (const float*)d_in[32];
  const float* gb = (const float*)d_in[33];
  const float* aW = (const float*)d_in[34];
  const float* ab = (const float*)d_in[35];
  const float* uW = (const float*)d_in[36];
  const float* ub = (const float*)d_in[37];

  char* ws = (char*)d_ws;
  const size_t szG  = (size_t)QG * NRG * 16;   // 557056
  const size_t szL0 = (size_t)Q0 * NR0 * 16;   // 59136
  const size_t szL1 = (size_t)Q1 * NR1 * 16;   // 52224
  const size_t szL2 = (size_t)Q2 * NR2 * 16;   // 188416
  const size_t offG = 0, offL0 = szG, offL1 = offL0 + szL0, offL2 = offL1 + szL1;
  const size_t offEx = offL2 + szL2;           // 856832
  const size_t exBytes = (size_t)B_ * EXSTRIDE * 4;  // 229376
  const size_t need = offEx + exBytes;         // 1086208

  if (ws_size >= need) {
    PArgs P;
    P.x = x; P.bih = bih; P.bhh = bhh;
    for (int nm = 0; nm < 4; ++nm) { P.b0[nm] = bb[0][nm]; P.b1[nm] = bb[1][nm]; P.b2[nm] = bb[2][nm]; }
    P.gW = gW; P.gb = gb; P.aW = aW; P.ab = ab; P.uW = uW; P.ub = ub;
    P.wsG  = (const uint4*)(ws + offG);
    P.wsL0 = (const uint4*)(ws + offL0);
    P.wsL1 = (const uint4*)(ws + offL1);
    P.wsL2 = (const uint4*)(ws + offL2);
    P.ex   = (int*)(ws + offEx);
    P.out  = (float*)d_out;

    hipMemsetAsync(ws + offEx, 0, exBytes, stream);
    int n;
    n = 136 * NRG;
    prep_gates3<<<(n + 255) / 256, 256, 0, stream>>>(Wih, Whh, (uint32_t*)(ws + offG));
    n = NR0 * 48;   // z0: 96 elems -> 48 pairs
    prep_cfc2<<<(n + 255) / 256, 256, 0, stream>>>(W[0][0], W[0][1], W[0][2], W[0][3], mk[0],
                                                   N0, DIN + N0, NR0, 48,
                                                   90, 0, 96, 0, 0,
                                                   (uint32_t*)(ws + offL0));
    n = NR1 * 64;   // z1: 128 elems
    prep_cfc2<<<(n + 255) / 256, 256, 0, stream>>>(W[1][0], W[1][1], W[1][2], W[1][3], mk[1],
                                                   N1, N0 + N1, NR1, 64,
                                                   51, 77, 51, 77, 0,
                                                   (uint32_t*)(ws + offL1));
    n = NR2 * 92;   // z2: 184 elems
    prep_cfc2<<<(n + 255) / 256, 256, 0, stream>>>(W[2][0], W[2][1], W[2][2], W[2][3], mk[2],
                                                   N2, N1 + N2, NR2, 92,
                                                   51, 0, 56, 128, 51,
                                                   (uint32_t*)(ws + offL2));
    int lds = (int)((sizeof(SMA) > sizeof(SMB)) ? sizeof(SMA) : sizeof(SMB));
    hipFuncSetAttribute(reinterpret_cast<const void*>(&rnn_coop),
                        hipFuncAttributeMaxDynamicSharedMemorySize, lds);
    rnn_coop<<<2 * B_, 512, lds, stream>>>(P);
    return;
  }

  // -------- fallback: direct f32 --------
  Args A;
  A.x = x; A.Wih = Wih; A.Whh = Whh; A.bih = bih; A.bhh = bhh;
  for (int nm = 0; nm < 4; ++nm) {
    A.W0[nm] = W[0][nm]; A.b0[nm] = bb[0][nm];
    A.W1[nm] = W[1][nm]; A.b1[nm] = bb[1][nm];
    A.W2[nm] = W[2][nm]; A.b2[nm] = bb[2][nm];
  }
  A.m0 = mk[0]; A.m1 = mk[1]; A.m2 = mk[2];
  A.gW = gW; A.gb = gb; A.aW = aW; A.ab = ab; A.uW = uW; A.ub = ub;
  A.out = (float*)d_out;
  hipFuncSetAttribute(reinterpret_cast<const void*>(&rnn_fallback),
                      hipFuncAttributeMaxDynamicSharedMemorySize, (int)sizeof(SMF));
  rnn_fallback<<<B_, 512, sizeof(SMF), stream>>>(A);
}

// Round 6
// 5964.274 us; speedup vs baseline: 8.5436x; 1.3405x over previous
//
#include <hip/hip_runtime.h>
#include <cstdint>

#define B_  128
#define T_  1024
#define DIN 13
#define HS  256
#define N0  77
#define N1  51
#define N2  128

// zg layout (f16 elems, 272 = 34 quads):
//   e0..12 x (13..15 pad) | e16..143 l2o | e144..194 l1o | e195..271 l0o
// quads: {0,1}=x  {2..17}=l2o  {18..24}=l1o(+l0o head)  {25..33}=l0o
#define QG   34
#define NRG  1024
// z0 (l0 in): e0..12 x | e13..89 h[0:77] | pad..95  -> 12 quads, 308 rows
#define Q0   12
#define NR0  308
// z1 (l1 in): e0..50 h[77:128] | e51..127 l0o  -> 16 quads, 204 rows
#define Q1   16
#define NR1  204
// z2 (l2 in): e0..50 l1o | 51..55 pad | e56..183 h[128:256] -> 23 quads, 512 rows
#define Q2   23
#define NR2  512
#define Q2LDS 18        // quads 0..17 LDS-resident in B; 18..22 streamed

// exchange (per b, stride 320 ints): [0..127] hop1 {l0o,l1o}, [128..255] hop2 l2o,
// flags in separate cache lines: f1 @256, f2 @272
#define EXSTRIDE 320
#define X1O   0
#define X2O   128
#define F1O   256
#define F2O   272

typedef _Float16 h2_t __attribute__((ext_vector_type(2)));

static __device__ __forceinline__ uint32_t pk2(float a, float b) {
  h2_t v; v.x = (_Float16)a; v.y = (_Float16)b;
  return __builtin_bit_cast(uint32_t, v);
}
static __device__ __forceinline__ unsigned short f16b(float v) {
  return __builtin_bit_cast(unsigned short, (_Float16)v);
}
static __device__ __forceinline__ void st16(void* base, int idx, unsigned short v) {
  ((unsigned short*)base)[idx] = v;
}
static __device__ __forceinline__ float dot2f(uint32_t w, uint32_t z, float acc) {
#if __has_builtin(__builtin_amdgcn_fdot2)
  return __builtin_amdgcn_fdot2(__builtin_bit_cast(h2_t, w), __builtin_bit_cast(h2_t, z), acc, false);
#else
  h2_t a = __builtin_bit_cast(h2_t, w), b = __builtin_bit_cast(h2_t, z);
  return acc + (float)a.x * (float)b.x + (float)a.y * (float)b.y;
#endif
}
static __device__ __forceinline__ float dot8f(uint4 w, uint4 z, float acc) {
  acc = dot2f(w.x, z.x, acc);
  acc = dot2f(w.y, z.y, acc);
  acc = dot2f(w.z, z.z, acc);
  acc = dot2f(w.w, z.w, acc);
  return acc;
}
static __device__ __forceinline__ float sigf(float x) { return 1.f / (1.f + expf(-x)); }

// fence-free exchange: relaxed agent-scope atomics (bypass stale caches without
// invalidating per-XCD L2 — round-2's acquire/release fences caused an HBM storm).
static __device__ __forceinline__ void axstore(int* p, float v) {
  __hip_atomic_store(p, __builtin_bit_cast(int, v), __ATOMIC_RELAXED, __HIP_MEMORY_SCOPE_AGENT);
}
static __device__ __forceinline__ void axstorei(int* p, int v) {
  __hip_atomic_store(p, v, __ATOMIC_RELAXED, __HIP_MEMORY_SCOPE_AGENT);
}
static __device__ __forceinline__ float axload(const int* p) {
  return __builtin_bit_cast(float, __hip_atomic_load((int*)p, __ATOMIC_RELAXED, __HIP_MEMORY_SCOPE_AGENT));
}
static __device__ __forceinline__ void vmw() {
  asm volatile("s_waitcnt vmcnt(0)" ::: "memory");
}
// all-thread poll: per-wave the 64 same-address lane loads coalesce to one request
static __device__ __forceinline__ void flag_wait(const int* p, int v) {
  while (__hip_atomic_load((int*)p, __ATOMIC_RELAXED, __HIP_MEMORY_SCOPE_AGENT) < v)
    __builtin_amdgcn_s_sleep(1);
}

// ---------------- prep kernels (layouts identical to round 5) ----------------

__global__ void prep_gates3(const float* __restrict__ Wih, const float* __restrict__ Whh,
                            uint32_t* __restrict__ out) {
  int id = blockIdx.x * blockDim.x + threadIdx.x;
  if (id >= 136 * NRG) return;
  int k2 = id >> 10, row = id & (NRG - 1);
  float v[2];
#pragma unroll
  for (int j = 0; j < 2; ++j) {
    int e = 2 * k2 + j;
    float val = 0.f;
    if (e < 13) val = Wih[row * DIN + e];
    else if (e >= 16 && e < 144) val = Whh[row * HS + 128 + (e - 16)];
    else if (e >= 144 && e < 195) val = Whh[row * HS + 77 + (e - 144)];
    else if (e >= 195 && e < 272) val = Whh[row * HS + (e - 195)];
    v[j] = val;
  }
  out[((k2 >> 2) * NRG + row) * 4 + (k2 & 3)] = pk2(v[0], v[1]);
}

__global__ void prep_cfc2(const float* __restrict__ Wf1, const float* __restrict__ Wf2,
                          const float* __restrict__ Wta, const float* __restrict__ Wtb,
                          const float* __restrict__ mask,
                          int nh, int K, int NR, int K2,
                          int p0n, int p0c, int p1s, int p1n, int p1c,
                          uint32_t* __restrict__ out) {
  int id = blockIdx.x * blockDim.x + threadIdx.x;
  if (id >= NR * K2) return;
  int k2 = id / NR, r = id % NR;
  int mat = r / nh, o = r % nh;
  const float* W = (mat == 0) ? Wf1 : (mat == 1) ? Wf2 : (mat == 2) ? Wta : Wtb;
  float v[2];
#pragma unroll
  for (int j = 0; j < 2; ++j) {
    int e = 2 * k2 + j;
    int col = -1;
    if (e < p0n) col = p0c + e;
    else if (e >= p1s && e < p1s + p1n) col = p1c + (e - p1s);
    float val = 0.f;
    if (col >= 0) {
      val = W[o * K + col];
      if (mat < 2) val *= mask[o * K + col];
    }
    v[j] = val;
  }
  out[((k2 >> 2) * NR + r) * 4 + (k2 & 3)] = pk2(v[0], v[1]);
}

// ---------------- shared structs ----------------

struct SMA {
  uint4 l0w[Q0 * NR0];   // 59136
  uint4 l1w[Q1 * NR1];   // 52224
  uint4 zb[2][QG];       // 1088
  uint4 z0[Q0];          // 192
  uint4 z1[Q1];          // 256
  float garr[512];       // 2048
  float ffb[NR0];        // 1232
  float cb0[NR0];
  float cb1[NR1];
};
struct SMB {
  uint4 l2w[Q2LDS * NR2];  // 147456
  uint4 zb[2][QG];         // 1088
  uint4 z2[Q2];            // 368
  float garr[512];
  float ffb[NR2];          // 2048
  float cb2[NR2];
  uint4 hwq[12][16];       // 3072
  float hb[12];
};
static_assert(sizeof(SMA) <= 163840, "SMA too big");
static_assert(sizeof(SMB) <= 163840, "SMB too big");

struct PArgs {
  const float* x;
  const float* bih; const float* bhh;
  const float* b0[4]; const float* b1[4]; const float* b2[4];
  const float* gW; const float* gb; const float* aW; const float* ab;
  const float* uW; const float* ub;
  const uint4* wsG; const uint4* wsL0; const uint4* wsL1; const uint4* wsL2;
  int* ex;
  float* out;
};

__global__ __launch_bounds__(512, 2) void rnn_coop2(PArgs P) {
  extern __shared__ char smraw[];
  const int tid = threadIdx.x;
  const bool isA = (blockIdx.x < B_);
  const int b = blockIdx.x & (B_ - 1);
  int* EX = P.ex + b * EXSTRIDE;
  int* F1 = EX + F1O;
  int* F2 = EX + F2O;
  const float* xb = P.x + (size_t)b * T_ * DIN;
  const size_t UNC_OFF = (size_t)B_ * T_ * 6;

  if (isA) {
    // ======== role A: gates rows(units 0..127) + LSTM[0:128] + l0 + l1 ========
    SMA& sm = *(SMA*)smraw;
    for (int i = tid; i < Q0 * NR0; i += 512) sm.l0w[i] = P.wsL0[i];
    for (int i = tid; i < Q1 * NR1; i += 512) sm.l1w[i] = P.wsL1[i];
    for (int i = tid; i < NR0; i += 512) sm.cb0[i] = P.b0[i / N0][i % N0];
    for (int i = tid; i < NR1; i += 512) sm.cb1[i] = P.b1[i / N1][i % N1];
    {
      uint32_t* zz = (uint32_t*)sm.zb;
      for (int i = tid; i < (2 * QG + Q0 + Q1) * 4; i += 512) zz[i] = 0u;
    }
    const int grow = ((tid >> 7) << 8) | (tid & 127);
    const float bg = P.bih[grow] + P.bhh[grow];
    float c_r = 0.f;
    __syncthreads();
    if (tid < 13) {
      unsigned short v = f16b(xb[tid]);
      st16(sm.zb[0], tid, v);
      st16(sm.z0, tid, v);
    }
    __syncthreads();
    float acc = bg;
    acc = dot8f(P.wsG[0 * NRG + grow], sm.zb[0][0], acc);
    acc = dot8f(P.wsG[1 * NRG + grow], sm.zb[0][1], acc);
    uint4* zbc = sm.zb[0];
    uint4* zbn = sm.zb[1];

    for (int t = 0; t < T_; ++t) {
      // 1: finish gates with l2o quads 2..17
#pragma unroll 8
      for (int q = 2; q < 18; ++q)
        acc = dot8f(P.wsG[q * NRG + grow], zbc[q], acc);
      sm.garr[tid] = acc;
      __syncthreads();
      // 2: LSTM[0:128] + x(t+1) prefetch + z0 x(t) copy
      if (tid < 128) {
        float gi = sm.garr[tid], gf = sm.garr[128 + tid];
        float gg = sm.garr[256 + tid], go = sm.garr[384 + tid];
        float cn = sigf(gf) * c_r + sigf(gi) * tanhf(gg);
        c_r = cn;
        float h = sigf(go) * tanhf(cn);
        if (tid < N0) st16(sm.z0, 13 + tid, f16b(h));
        else          st16(sm.z1, tid - N0, f16b(h));
      } else if (tid >= 320 && tid < 336) {
        int i = tid - 320;
        if (i < 13) {
          float xv = (t + 1 < T_) ? xb[(size_t)(t + 1) * DIN + i] : 0.f;
          st16(zbn, i, f16b(xv));
        }
      } else if (tid >= 336 && tid < 352) {
        int i = tid - 336;
        if (i < 13) st16(sm.z0, i, ((unsigned short*)zbc)[i]);
      }
      __syncthreads();
      // 3: l0 matvec (308 rows)
      if (tid < NR0) {
        float a = sm.cb0[tid];
#pragma unroll
        for (int q = 0; q < Q0; ++q) a = dot8f(sm.l0w[q * NR0 + tid], sm.z0[q], a);
        sm.ffb[tid] = (tid < 2 * N0) ? tanhf(a) : a;
      }
      __syncthreads();
      // 4: combine l0 -> l0o (z1, zbn, EX hop1 part)
      if (tid < N0) {
        float ti = sigf(sm.ffb[2 * N0 + tid] + sm.ffb[3 * N0 + tid]);
        float v = sm.ffb[tid] * (1.f - ti) + ti * sm.ffb[N0 + tid];
        unsigned short v16 = f16b(v);
        st16(sm.z1, 51 + tid, v16);
        st16(zbn, 195 + tid, v16);
        axstore(EX + X1O + tid, v);
      }
      __syncthreads();
      // 5: l1 matvec (204 rows)
      if (tid < NR1) {
        float a = sm.cb1[tid];
#pragma unroll
        for (int q = 0; q < Q1; ++q) a = dot8f(sm.l1w[q * NR1 + tid], sm.z1[q], a);
        sm.ffb[tid] = (tid < 2 * N1) ? tanhf(a) : a;
      }
      __syncthreads();
      // 6: combine l1 -> l1o; publish hop1
      if (tid < N1) {
        float ti = sigf(sm.ffb[2 * N1 + tid] + sm.ffb[3 * N1 + tid]);
        float v = sm.ffb[tid] * (1.f - ti) + ti * sm.ffb[N1 + tid];
        st16(zbn, 144 + tid, f16b(v));
        axstore(EX + X1O + N0 + tid, v);
      }
      vmw();
      __syncthreads();
      if (tid == 0) axstorei(F1, t + 1);
      // 7: gates(t+1) local partial: x + l1o + l0o quads (overlaps B's l2 + hop2)
      acc = bg;
      acc = dot8f(P.wsG[0 * NRG + grow], zbn[0], acc);
      acc = dot8f(P.wsG[1 * NRG + grow], zbn[1], acc);
#pragma unroll 8
      for (int q = 18; q < 34; ++q)
        acc = dot8f(P.wsG[q * NRG + grow], zbn[q], acc);
      // 8: receive l2o (hop2)
      flag_wait(F2, t + 1);
      if (tid < 128) st16(zbn, 16 + tid, f16b(axload(EX + X2O + tid)));
      __syncthreads();
      uint4* tmp = zbc; zbc = zbn; zbn = tmp;
    }
  } else {
    // ======== role B: gates rows(units 128..255) + LSTM[128:256] + l2 full + heads ========
    SMB& sm = *(SMB*)smraw;
    for (int i = tid; i < Q2LDS * NR2; i += 512) sm.l2w[i] = P.wsL2[i];
    for (int i = tid; i < NR2; i += 512) sm.cb2[i] = P.b2[i >> 7][i & 127];
    for (int i = tid; i < 768; i += 512) {
      int r = i >> 6, w = i & 63;
      const float* W = (r < 3) ? P.gW + r * 128 : (r < 6) ? P.aW + (r - 3) * 128 : P.uW + (r - 6) * 128;
      ((uint32_t*)sm.hwq)[i] = pk2(W[2 * w], W[2 * w + 1]);
    }
    if (tid < 12) sm.hb[tid] = (tid < 3) ? P.gb[tid] : (tid < 6) ? P.ab[tid - 3] : P.ub[tid - 6];
    {
      uint32_t* zz = (uint32_t*)sm.zb;
      for (int i = tid; i < (2 * QG + Q2) * 4; i += 512) zz[i] = 0u;
    }
    const int grow = ((tid >> 7) << 8) | 128 | (tid & 127);
    const float bg = P.bih[grow] + P.bhh[grow];
    float c_r = 0.f;
    __syncthreads();
    if (tid < 13) st16(sm.zb[0], tid, f16b(xb[tid]));
    __syncthreads();
    uint4* zbc = sm.zb[0];
    uint4* zbn = sm.zb[1];

    for (int t = 0; t < T_; ++t) {
      // 1: full gates (34 quads; all z(t) parts local by construction) + heads(t-1)
      float acc = bg;
      if (tid < 12 && t > 0) {
        int r = tid;
        float a = sm.hb[r];
#pragma unroll
        for (int q = 0; q < 16; ++q) a = dot8f(sm.hwq[r][q], zbc[2 + q], a);
        size_t base = ((size_t)b * T_ + (t - 1)) * 6;
        if (r < 6) P.out[base + r] = a;
        else {
          float sp = (a > 0.f) ? (a + log1pf(expf(-a))) : log1pf(expf(a));
          P.out[UNC_OFF + base + (r - 6)] = sp;
        }
      }
#pragma unroll 8
      for (int q = 0; q < QG; ++q)
        acc = dot8f(P.wsG[q * NRG + grow], zbc[q], acc);
      sm.garr[tid] = acc;
      __syncthreads();
      // 2: LSTM[128:256] -> z2 h-part; x(t+1) prefetch
      if (tid < 128) {
        float gi = sm.garr[tid], gf = sm.garr[128 + tid];
        float gg = sm.garr[256 + tid], go = sm.garr[384 + tid];
        float cn = sigf(gf) * c_r + sigf(gi) * tanhf(gg);
        c_r = cn;
        float h = sigf(go) * tanhf(cn);
        st16(sm.z2, 56 + tid, f16b(h));
      } else if (tid >= 192 && tid < 208) {
        int i = tid - 192;
        if (i < 13) {
          float xv = (t + 1 < T_) ? xb[(size_t)(t + 1) * DIN + i] : 0.f;
          st16(zbn, i, f16b(xv));
        }
      }
      __syncthreads();
      // 3: l2 partial over h2 quads (7..17 LDS, 18..22 streamed) — overlaps hop1 wait
      float a2 = sm.cb2[tid];
#pragma unroll
      for (int q = 7; q < Q2LDS; ++q) a2 = dot8f(sm.l2w[q * NR2 + tid], sm.z2[q], a2);
#pragma unroll
      for (int q = Q2LDS; q < Q2; ++q) a2 = dot8f(P.wsL2[q * NR2 + tid], sm.z2[q], a2);
      // 4: receive hop1 {l0o, l1o}
      flag_wait(F1, t + 1);
      if (tid < N0) {
        st16(zbn, 195 + tid, f16b(axload(EX + X1O + tid)));
      } else if (tid < 128) {
        int j = tid - N0;
        float v = axload(EX + X1O + N0 + j);
        unsigned short v16 = f16b(v);
        st16(sm.z2, j, v16);
        st16(zbn, 144 + j, v16);
      }
      __syncthreads();
      // 5: finish l2 (l1o quads 0..6, LDS)
#pragma unroll
      for (int q = 0; q < 7; ++q) a2 = dot8f(sm.l2w[q * NR2 + tid], sm.z2[q], a2);
      sm.ffb[tid] = (tid < 2 * N2) ? tanhf(a2) : a2;
      __syncthreads();
      // 6: combine l2 -> l2o; publish hop2
      if (tid < N2) {
        float ti = sigf(sm.ffb[2 * N2 + tid] + sm.ffb[3 * N2 + tid]);
        float v = sm.ffb[tid] * (1.f - ti) + ti * sm.ffb[N2 + tid];
        st16(zbn, 16 + tid, f16b(v));
        axstore(EX + X2O + tid, v);
      }
      vmw();
      __syncthreads();
      if (tid == 0) axstorei(F2, t + 1);
      uint4* tmp = zbc; zbc = zbn; zbn = tmp;
    }
    // tail: heads for t = T_-1 (l2o in zbc after final swap)
    if (tid < 12) {
      int r = tid;
      float a = sm.hb[r];
#pragma unroll
      for (int q = 0; q < 16; ++q) a = dot8f(sm.hwq[r][q], zbc[2 + q], a);
      size_t base = ((size_t)b * T_ + (T_ - 1)) * 6;
      if (r < 6) P.out[base + r] = a;
      else {
        float sp = (a > 0.f) ? (a + log1pf(expf(-a))) : log1pf(expf(a));
        P.out[UNC_OFF + base + (r - 6)] = sp;
      }
    }
  }
}

// ================= fallback: direct f32 kernel (no workspace) =================

struct Args {
  const float* x;
  const float* Wih; const float* Whh; const float* bih; const float* bhh;
  const float* W0[4]; const float* b0[4]; const float* m0;
  const float* W1[4]; const float* b1[4]; const float* m1;
  const float* W2[4]; const float* b2[4]; const float* m2;
  const float* gW; const float* gb; const float* aW; const float* ab;
  const float* uW; const float* ub;
  float* out;
};

struct SMF {
  float xt[16];
  float lstm_h[HS];
  float hprev[HS];
  float garr[4 * HS];
  float ffb[4][128];
  float cb0[NR0];
  float cb1[NR1];
  float cb2[NR2];
  float hw[12][132];
  float hb[12];
};

__global__ __launch_bounds__(512, 2) void rnn_fallback(Args A) {
  extern __shared__ char smraw[];
  SMF& sm = *(SMF*)smraw;
  const int tid = threadIdx.x;
  const int b = blockIdx.x;

  for (int i = tid; i < NR0; i += 512) sm.cb0[i] = A.b0[i / N0][i % N0];
  for (int i = tid; i < NR1; i += 512) sm.cb1[i] = A.b1[i / N1][i % N1];
  for (int i = tid; i < NR2; i += 512) sm.cb2[i] = A.b2[i / N2][i % N2];
  for (int i = tid; i < 12 * 128; i += 512) {
    int r = i >> 7, k = i & 127;
    sm.hw[r][k] = (r < 3) ? A.gW[r * 128 + k]
                : (r < 6) ? A.aW[(r - 3) * 128 + k]
                          : A.uW[(r - 6) * 128 + k];
  }
  if (tid < 12) sm.hb[tid] = (tid < 3) ? A.gb[tid] : (tid < 6) ? A.ab[tid - 3] : A.ub[tid - 6];
  for (int i = tid; i < HS; i += 512) sm.hprev[i] = 0.f;
  float bga = A.bih[tid] + A.bhh[tid];
  float bgb = A.bih[tid + 512] + A.bhh[tid + 512];
  float c_r = 0.f;
  __syncthreads();

  const float* xb = A.x + (size_t)b * T_ * DIN;
  const size_t UNC_OFF = (size_t)B_ * T_ * 6;

  for (int t = 0; t < T_; ++t) {
    const float* xp = xb + (size_t)t * DIN;
    if (tid < DIN) sm.xt[tid] = xp[tid];
    __syncthreads();

    float aa = bga, ab = bgb;
    for (int k = 0; k < DIN; ++k) {
      float xv = sm.xt[k];
      aa += A.Wih[tid * DIN + k] * xv;
      ab += A.Wih[(tid + 512) * DIN + k] * xv;
    }
    for (int k = 0; k < HS; ++k) {
      float hv = sm.hprev[k];
      aa += A.Whh[tid * HS + k] * hv;
      ab += A.Whh[(tid + 512) * HS + k] * hv;
    }
    sm.garr[tid] = aa;
    sm.garr[tid + 512] = ab;
    __syncthreads();

    if (tid < HS) {
      float gi = sm.garr[tid], gf = sm.garr[HS + tid];
      float gg = sm.garr[2 * HS + tid], go = sm.garr[3 * HS + tid];
      float cn = sigf(gf) * c_r + sigf(gi) * tanhf(gg);
      c_r = cn;
      sm.lstm_h[tid] = sigf(go) * tanhf(cn);
    }
    __syncthreads();

    if (tid < NR0) {
      int mat = tid / N0, o = tid % N0;
      const float* W = A.W0[mat];
      const float* m = A.m0;
      const int Kl = DIN + N0;
      float acc = sm.cb0[tid];
      for (int k = 0; k < DIN; ++k) {
        float w = W[o * Kl + k];
        if (mat < 2) w *= m[o * Kl + k];
        acc += w * sm.xt[k];
      }
      for (int k = DIN; k < Kl; ++k) acc += W[o * Kl + k] * sm.lstm_h[k - DIN];
      sm.ffb[mat][o] = (mat < 2) ? tanhf(acc) : acc;
    }
    __syncthreads();
    if (tid < N0) {
      float ti = sigf(sm.ffb[2][tid] + sm.ffb[3][tid]);
      sm.hprev[tid] = sm.ffb[0][tid] * (1.f - ti) + ti * sm.ffb[1][tid];
    }
    __syncthreads();

    if (tid < NR1) {
      int mat = tid / N1, o = tid % N1;
      const float* W = A.W1[mat];
      const float* m = A.m1;
      const int Kl = N0 + N1;
      float acc = sm.cb1[tid];
      for (int k = 0; k < N0; ++k) {
        float w = W[o * Kl + k];
        if (mat < 2) w *= m[o * Kl + k];
        acc += w * sm.hprev[k];
      }
      for (int k = N0; k < Kl; ++k) acc += W[o * Kl + k] * sm.lstm_h[k];
      sm.ffb[mat][o] = (mat < 2) ? tanhf(acc) : acc;
    }
    __syncthreads();
    if (tid < N1) {
      float ti = sigf(sm.ffb[2][tid] + sm.ffb[3][tid]);
      sm.hprev[N0 + tid] = sm.ffb[0][tid] * (1.f - ti) + ti * sm.ffb[1][tid];
    }
    __syncthreads();

    {
      int mat = tid >> 7, o = tid & 127;
      const float* W = A.W2[mat];
      const float* m = A.m2;
      const int Kl = N1 + N2;
      float acc = sm.cb2[tid];
      for (int k = 0; k < N1; ++k) {
        float w = W[o * Kl + k];
        if (mat < 2) w *= m[o * Kl + k];
        acc += w * sm.hprev[N0 + k];
      }
      for (int k = N1; k < Kl; ++k) acc += W[o * Kl + k] * sm.lstm_h[N0 + k];
      sm.ffb[mat][o] = (mat < 2) ? tanhf(acc) : acc;
    }
    __syncthreads();
    if (tid < N2) {
      float ti = sigf(sm.ffb[2][tid] + sm.ffb[3][tid]);
      sm.hprev[N0 + N1 + tid] = sm.ffb[0][tid] * (1.f - ti) + ti * sm.ffb[1][tid];
    }
    __syncthreads();

    if (tid >= 256 && tid < 268) {
      int r = tid - 256;
      const float* mo = &sm.hprev[N0 + N1];
      float acc = sm.hb[r];
      for (int k = 0; k < 128; ++k) acc += sm.hw[r][k] * mo[k];
      size_t base = ((size_t)b * T_ + t) * 6;
      if (r < 6) A.out[base + r] = acc;
      else {
        float sp = (acc > 0.f) ? (acc + log1pf(expf(-acc))) : log1pf(expf(acc));
        A.out[UNC_OFF + base + (r - 6)] = sp;
      }
    }
    __syncthreads();
  }
}

// ---------------- launcher ----------------

extern "C" void kernel_launch(void* const* d_in, const int* in_sizes, int n_in,
                              void* d_out, int out_size, void* d_ws, size_t ws_size,
                              hipStream_t stream) {
  const float* x   = (const float*)d_in[0];
  const float* Wih = (const float*)d_in[1];
  const float* Whh = (const float*)d_in[2];
  const float* bih = (const float*)d_in[3];
  const float* bhh = (const float*)d_in[4];
  const float *W[3][4], *bb[3][4], *mk[3];
  for (int l = 0; l < 3; ++l) {
    int base = 5 + l * 9;
    for (int nm = 0; nm < 4; ++nm) {
      W[l][nm]  = (const float*)d_in[base + 2 * nm];
      bb[l][nm] = (const float*)d_in[base + 2 * nm + 1];
    }
    mk[l] = (const float*)d_in[base + 8];
  }
  const float* gW = (const float*)d_in[32];
  const float* gb = (const float*)d_in[33];
  const float* aW = (const float*)d_in[34];
  const float* ab = (const float*)d_in[35];
  const float* uW = (const float*)d_in[36];
  const float* ub = (const float*)d_in[37];

  char* ws = (char*)d_ws;
  const size_t szG  = (size_t)QG * NRG * 16;   // 557056
  const size_t szL0 = (size_t)Q0 * NR0 * 16;   // 59136
  const size_t szL1 = (size_t)Q1 * NR1 * 16;   // 52224
  const size_t szL2 = (size_t)Q2 * NR2 * 16;   // 188416
  const size_t offG = 0, offL0 = szG, offL1 = offL0 + szL0, offL2 = offL1 + szL1;
  const size_t offEx = offL2 + szL2;           // 856832
  const size_t exBytes = (size_t)B_ * EXSTRIDE * 4;  // 163840
  const size_t need = offEx + exBytes;         // 1020672

  if (ws_size >= need) {
    PArgs P;
    P.x = x; P.bih = bih; P.bhh = bhh;
    for (int nm = 0; nm < 4; ++nm) { P.b0[nm] = bb[0][nm]; P.b1[nm] = bb[1][nm]; P.b2[nm] = bb[2][nm]; }
    P.gW = gW; P.gb = gb; P.aW = aW; P.ab = ab; P.uW = uW; P.ub = ub;
    P.wsG  = (const uint4*)(ws + offG);
    P.wsL0 = (const uint4*)(ws + offL0);
    P.wsL1 = (const uint4*)(ws + offL1);
    P.wsL2 = (const uint4*)(ws + offL2);
    P.ex   = (int*)(ws + offEx);
    P.out  = (float*)d_out;

    hipMemsetAsync(ws + offEx, 0, exBytes, stream);
    int n;
    n = 136 * NRG;
    prep_gates3<<<(n + 255) / 256, 256, 0, stream>>>(Wih, Whh, (uint32_t*)(ws + offG));
    n = NR0 * 48;
    prep_cfc2<<<(n + 255) / 256, 256, 0, stream>>>(W[0][0], W[0][1], W[0][2], W[0][3], mk[0],
                                                   N0, DIN + N0, NR0, 48,
                                                   90, 0, 96, 0, 0,
                                                   (uint32_t*)(ws + offL0));
    n = NR1 * 64;
    prep_cfc2<<<(n + 255) / 256, 256, 0, stream>>>(W[1][0], W[1][1], W[1][2], W[1][3], mk[1],
                                                   N1, N0 + N1, NR1, 64,
                                                   51, 77, 51, 77, 0,
                                                   (uint32_t*)(ws + offL1));
    n = NR2 * 92;
    prep_cfc2<<<(n + 255) / 256, 256, 0, stream>>>(W[2][0], W[2][1], W[2][2], W[2][3], mk[2],
                                                   N2, N1 + N2, NR2, 92,
                                                   51, 0, 56, 128, 51,
                                                   (uint32_t*)(ws + offL2));
    int lds = (int)((sizeof(SMA) > sizeof(SMB)) ? sizeof(SMA) : sizeof(SMB));
    hipFuncSetAttribute(reinterpret_cast<const void*>(&rnn_coop2),
                        hipFuncAttributeMaxDynamicSharedMemorySize, lds);
    rnn_coop2<<<2 * B_, 512, lds, stream>>>(P);
    return;
  }

  // -------- fallback: direct f32 --------
  Args A;
  A.x = x; A.Wih = Wih; A.Whh = Whh; A.bih = bih; A.bhh = bhh;
  for (int nm = 0; nm < 4; ++nm) {
    A.W0[nm] = W[0][nm]; A.b0[nm] = bb[0][nm];
    A.W1[nm] = W[1][nm]; A.b1[nm] = bb[1][nm];
    A.W2[nm] = W[2][nm]; A.b2[nm] = bb[2][nm];
  }
  A.m0 = mk[0]; A.m1 = mk[1]; A.m2 = mk[2];
  A.gW = gW; A.gb = gb; A.aW = aW; A.ab = ab; A.uW = uW; A.ub = ub;
  A.out = (float*)d_out;
  hipFuncSetAttribute(reinterpret_cast<const void*>(&rnn_fallback),
                      hipFuncAttributeMaxDynamicSharedMemorySize, (int)sizeof(SMF));
  rnn_fallback<<<B_, 512, sizeof(SMF), stream>>>(A);
}

// Round 7
// 5430.341 us; speedup vs baseline: 9.3837x; 1.0983x over previous
//
#include <hip/hip_runtime.h>
#include <cstdint>

#define B_  128
#define T_  1024
#define DIN 13
#define HS  256
#define N0  77
#define N1  51
#define N2  128

// zg layout (f16 elems, 272 = 34 quads):
//   e0..12 x (13..15 pad) | e16..143 l2o | e144..194 l1o | e195..271 l0o
// quads: {0,1}=x  {2..17}=l2o  {18..24}=l1o(+l0o head)  {25..33}=l0o
#define QG   34
#define NRG  1024
// z0 (l0 in): e0..12 x | e13..89 h[0:77] | pad..95  -> 12 quads, 308 rows
#define Q0   12
#define NR0  308
// z1 (l1 in): e0..50 h[77:128] | e51..127 l0o  -> 16 quads, 204 rows
#define Q1   16
#define NR1  204
// z2 (l2 in): e0..50 l1o | 51..55 pad | e56..183 h[128:256] -> 23 quads, 512 rows
#define Q2   23
#define NR2  512
#define Q2LDS 18        // quads 0..17 LDS-resident in B; 18..22 streamed

// exchange (per b, stride 256 ints). Each word = (tag<<16) | f16bits.
// hop1 [0..127] = {l0o(77), l1o(51)}; hop2 [128..255] = l2o(128).
#define EXSTRIDE 256
#define X1O   0
#define X2O   128

typedef _Float16 h2_t __attribute__((ext_vector_type(2)));

static __device__ __forceinline__ uint32_t pk2(float a, float b) {
  h2_t v; v.x = (_Float16)a; v.y = (_Float16)b;
  return __builtin_bit_cast(uint32_t, v);
}
static __device__ __forceinline__ unsigned short f16b(float v) {
  return __builtin_bit_cast(unsigned short, (_Float16)v);
}
static __device__ __forceinline__ void st16(void* base, int idx, unsigned short v) {
  ((unsigned short*)base)[idx] = v;
}
static __device__ __forceinline__ float dot2f(uint32_t w, uint32_t z, float acc) {
#if __has_builtin(__builtin_amdgcn_fdot2)
  return __builtin_amdgcn_fdot2(__builtin_bit_cast(h2_t, w), __builtin_bit_cast(h2_t, z), acc, false);
#else
  h2_t a = __builtin_bit_cast(h2_t, w), b = __builtin_bit_cast(h2_t, z);
  return acc + (float)a.x * (float)b.x + (float)a.y * (float)b.y;
#endif
}
static __device__ __forceinline__ float dot8f(uint4 w, uint4 z, float acc) {
  acc = dot2f(w.x, z.x, acc);
  acc = dot2f(w.y, z.y, acc);
  acc = dot2f(w.z, z.z, acc);
  acc = dot2f(w.w, z.w, acc);
  return acc;
}
static __device__ __forceinline__ float sigf(float x) { return 1.f / (1.f + expf(-x)); }

// tagged-word exchange: relaxed agent-scope atomics (coherent, no L2 invalidation).
// One word carries both "ready" (tag == t+1) and the f16 payload -> one L3 round
// trip per hop instead of flag+payload two.
static __device__ __forceinline__ void axpub(int* p, int tag, unsigned short v16) {
  __hip_atomic_store(p, (tag << 16) | (int)v16, __ATOMIC_RELAXED, __HIP_MEMORY_SCOPE_AGENT);
}
static __device__ __forceinline__ unsigned short axpoll(const int* p, int tag) {
  int w;
  do {
    w = __hip_atomic_load((int*)p, __ATOMIC_RELAXED, __HIP_MEMORY_SCOPE_AGENT);
  } while (((unsigned)w >> 16) != (unsigned)tag);
  return (unsigned short)(w & 0xFFFF);
}

// ---------------- prep kernels (layouts identical to round 6) ----------------

__global__ void prep_gates3(const float* __restrict__ Wih, const float* __restrict__ Whh,
                            uint32_t* __restrict__ out) {
  int id = blockIdx.x * blockDim.x + threadIdx.x;
  if (id >= 136 * NRG) return;
  int k2 = id >> 10, row = id & (NRG - 1);
  float v[2];
#pragma unroll
  for (int j = 0; j < 2; ++j) {
    int e = 2 * k2 + j;
    float val = 0.f;
    if (e < 13) val = Wih[row * DIN + e];
    else if (e >= 16 && e < 144) val = Whh[row * HS + 128 + (e - 16)];
    else if (e >= 144 && e < 195) val = Whh[row * HS + 77 + (e - 144)];
    else if (e >= 195 && e < 272) val = Whh[row * HS + (e - 195)];
    v[j] = val;
  }
  out[((k2 >> 2) * NRG + row) * 4 + (k2 & 3)] = pk2(v[0], v[1]);
}

__global__ void prep_cfc2(const float* __restrict__ Wf1, const float* __restrict__ Wf2,
                          const float* __restrict__ Wta, const float* __restrict__ Wtb,
                          const float* __restrict__ mask,
                          int nh, int K, int NR, int K2,
                          int p0n, int p0c, int p1s, int p1n, int p1c,
                          uint32_t* __restrict__ out) {
  int id = blockIdx.x * blockDim.x + threadIdx.x;
  if (id >= NR * K2) return;
  int k2 = id / NR, r = id % NR;
  int mat = r / nh, o = r % nh;
  const float* W = (mat == 0) ? Wf1 : (mat == 1) ? Wf2 : (mat == 2) ? Wta : Wtb;
  float v[2];
#pragma unroll
  for (int j = 0; j < 2; ++j) {
    int e = 2 * k2 + j;
    int col = -1;
    if (e < p0n) col = p0c + e;
    else if (e >= p1s && e < p1s + p1n) col = p1c + (e - p1s);
    float val = 0.f;
    if (col >= 0) {
      val = W[o * K + col];
      if (mat < 2) val *= mask[o * K + col];
    }
    v[j] = val;
  }
  out[((k2 >> 2) * NR + r) * 4 + (k2 & 3)] = pk2(v[0], v[1]);
}

// ---------------- shared structs ----------------

struct SMA {
  uint4 l0w[Q0 * NR0];   // 59136
  uint4 l1w[Q1 * NR1];   // 52224
  uint4 zb[2][QG];       // 1088
  uint4 z0[Q0];          // 192
  uint4 z1[Q1];          // 256
  float garr[512];       // 2048
  float ffb[NR0];        // 1232
  float cb0[NR0];
  float cb1[NR1];
};
struct SMB {
  uint4 l2w[Q2LDS * NR2];  // 147456
  uint4 zb[2][QG];         // 1088
  uint4 z2[Q2];            // 368
  float garr[512];
  float ffb[NR2];          // 2048
  float cb2[NR2];
  uint4 hwq[12][16];       // 3072
  float hb[12];
};
static_assert(sizeof(SMA) <= 163840, "SMA too big");
static_assert(sizeof(SMB) <= 163840, "SMB too big");

struct PArgs {
  const float* x;
  const float* bih; const float* bhh;
  const float* b0[4]; const float* b1[4]; const float* b2[4];
  const float* gW; const float* gb; const float* aW; const float* ab;
  const float* uW; const float* ub;
  const uint4* wsG; const uint4* wsL0; const uint4* wsL1; const uint4* wsL2;
  int* ex;
  float* out;
};

__global__ __launch_bounds__(512, 2) void rnn_coop3(PArgs P) {
  extern __shared__ char smraw[];
  const int tid = threadIdx.x;
  const bool isA = (blockIdx.x < B_);
  const int b = blockIdx.x & (B_ - 1);
  int* EX = P.ex + b * EXSTRIDE;
  const float* xb = P.x + (size_t)b * T_ * DIN;
  const size_t UNC_OFF = (size_t)B_ * T_ * 6;

  if (isA) {
    // ======== role A: gate rows (units 0..127) + LSTM[0:128] + l0 + l1 ========
    SMA& sm = *(SMA*)smraw;
    for (int i = tid; i < Q0 * NR0; i += 512) sm.l0w[i] = P.wsL0[i];
    for (int i = tid; i < Q1 * NR1; i += 512) sm.l1w[i] = P.wsL1[i];
    for (int i = tid; i < NR0; i += 512) sm.cb0[i] = P.b0[i / N0][i % N0];
    for (int i = tid; i < NR1; i += 512) sm.cb1[i] = P.b1[i / N1][i % N1];
    {
      uint32_t* zz = (uint32_t*)sm.zb;
      for (int i = tid; i < (2 * QG + Q0 + Q1) * 4; i += 512) zz[i] = 0u;
    }
    const int grow = ((tid >> 7) << 8) | (tid & 127);
    const float bg = P.bih[grow] + P.bhh[grow];
    float c_r = 0.f;
    __syncthreads();
    if (tid < 13) st16(sm.zb[0], tid, f16b(xb[tid]));
    __syncthreads();
    uint4* zbc = sm.zb[0];
    uint4* zbn = sm.zb[1];
    // prologue: gates(0) = bg + x quads (h regions zero)
    {
      float acc = bg;
      acc = dot8f(P.wsG[0 * NRG + grow], zbc[0], acc);
      acc = dot8f(P.wsG[1 * NRG + grow], zbc[1], acc);
      sm.garr[tid] = acc;
    }
    __syncthreads();

    for (int t = 0; t < T_; ++t) {
      // 1: LSTM[0:128] (garr holds gates(t)) + x(t+1)->zbn + x(t) zbc->z0
      if (tid < 128) {
        float gi = sm.garr[tid], gf = sm.garr[128 + tid];
        float gg = sm.garr[256 + tid], go = sm.garr[384 + tid];
        float cn = sigf(gf) * c_r + sigf(gi) * tanhf(gg);
        c_r = cn;
        float h = sigf(go) * tanhf(cn);
        if (tid < N0) st16(sm.z0, 13 + tid, f16b(h));
        else          st16(sm.z1, tid - N0, f16b(h));
      } else if (tid >= 320 && tid < 336) {
        int i = tid - 320;
        if (i < 13) {
          float xv = (t + 1 < T_) ? xb[(size_t)(t + 1) * DIN + i] : 0.f;
          st16(zbn, i, f16b(xv));
        }
      } else if (tid >= 336 && tid < 352) {
        int i = tid - 336;
        if (i < 13) st16(sm.z0, i, ((unsigned short*)zbc)[i]);
      }
      __syncthreads();
      // 2: l0 matvec
      if (tid < NR0) {
        float a = sm.cb0[tid];
#pragma unroll
        for (int q = 0; q < Q0; ++q) a = dot8f(sm.l0w[q * NR0 + tid], sm.z0[q], a);
        sm.ffb[tid] = (tid < 2 * N0) ? tanhf(a) : a;
      }
      __syncthreads();
      // 3: combine l0 -> publish tagged immediately
      if (tid < N0) {
        float ti = sigf(sm.ffb[2 * N0 + tid] + sm.ffb[3 * N0 + tid]);
        float v = sm.ffb[tid] * (1.f - ti) + ti * sm.ffb[N0 + tid];
        unsigned short v16 = f16b(v);
        axpub(EX + X1O + tid, t + 1, v16);
        st16(sm.z1, 51 + tid, v16);
        st16(zbn, 195 + tid, v16);
      }
      __syncthreads();
      // 4: l1 matvec
      if (tid < NR1) {
        float a = sm.cb1[tid];
#pragma unroll
        for (int q = 0; q < Q1; ++q) a = dot8f(sm.l1w[q * NR1 + tid], sm.z1[q], a);
        sm.ffb[tid] = (tid < 2 * N1) ? tanhf(a) : a;
      }
      __syncthreads();
      // 5: combine l1 -> publish tagged
      if (tid < N1) {
        float ti = sigf(sm.ffb[2 * N1 + tid] + sm.ffb[3 * N1 + tid]);
        float v = sm.ffb[tid] * (1.f - ti) + ti * sm.ffb[N1 + tid];
        unsigned short v16 = f16b(v);
        axpub(EX + X1O + N0 + tid, t + 1, v16);
        st16(zbn, 144 + tid, v16);
      }
      __syncthreads();
      // 6: prefetch l2o-gate weights (regs) + local gates(t+1) partial (x,l1o,l0o)
      uint4 pw[16];
#pragma unroll
      for (int q = 0; q < 16; ++q) pw[q] = P.wsG[(2 + q) * NRG + grow];
      float acc = bg;
      acc = dot8f(P.wsG[0 * NRG + grow], zbn[0], acc);
      acc = dot8f(P.wsG[1 * NRG + grow], zbn[1], acc);
#pragma unroll 8
      for (int q = 18; q < 34; ++q)
        acc = dot8f(P.wsG[q * NRG + grow], zbn[q], acc);
      asm volatile("" ::: "memory");   // keep pw loads issued before the poll
      // 7: poll hop2 (l2o(t), one round trip: tag+payload fused)
      if (tid < 128) {
        unsigned short v16 = axpoll(EX + X2O + tid, t + 1);
        st16(zbn, 16 + tid, v16);
      }
      __syncthreads();
      // 8: finish gates(t+1) with prefetched weights
#pragma unroll
      for (int q = 0; q < 16; ++q) acc = dot8f(pw[q], zbn[2 + q], acc);
      sm.garr[tid] = acc;
      __syncthreads();
      uint4* tmp = zbc; zbc = zbn; zbn = tmp;
    }
  } else {
    // ======== role B: gate rows (units 128..255) + LSTM[128:256] + full l2 + heads ========
    SMB& sm = *(SMB*)smraw;
    for (int i = tid; i < Q2LDS * NR2; i += 512) sm.l2w[i] = P.wsL2[i];
    for (int i = tid; i < NR2; i += 512) sm.cb2[i] = P.b2[i >> 7][i & 127];
    for (int i = tid; i < 768; i += 512) {
      int r = i >> 6, w = i & 63;
      const float* W = (r < 3) ? P.gW + r * 128 : (r < 6) ? P.aW + (r - 3) * 128 : P.uW + (r - 6) * 128;
      ((uint32_t*)sm.hwq)[i] = pk2(W[2 * w], W[2 * w + 1]);
    }
    if (tid < 12) sm.hb[tid] = (tid < 3) ? P.gb[tid] : (tid < 6) ? P.ab[tid - 3] : P.ub[tid - 6];
    {
      uint32_t* zz = (uint32_t*)sm.zb;
      for (int i = tid; i < (2 * QG + Q2) * 4; i += 512) zz[i] = 0u;
    }
    const int grow = ((tid >> 7) << 8) | 128 | (tid & 127);
    const float bg = P.bih[grow] + P.bhh[grow];
    float c_r = 0.f;
    __syncthreads();
    if (tid < 13) st16(sm.zb[0], tid, f16b(xb[tid]));
    __syncthreads();
    uint4* zbc = sm.zb[0];
    uint4* zbn = sm.zb[1];

    for (int t = 0; t < T_; ++t) {
      // 1: full gates(t) (all z(t) local) + heads(t-1)
      float acc = bg;
#pragma unroll 8
      for (int q = 0; q < QG; ++q)
        acc = dot8f(P.wsG[q * NRG + grow], zbc[q], acc);
      if (tid < 12 && t > 0) {
        int r = tid;
        float a = sm.hb[r];
#pragma unroll
        for (int q = 0; q < 16; ++q) a = dot8f(sm.hwq[r][q], zbc[2 + q], a);
        size_t base = ((size_t)b * T_ + (t - 1)) * 6;
        if (r < 6) P.out[base + r] = a;
        else {
          float sp = (a > 0.f) ? (a + log1pf(expf(-a))) : log1pf(expf(a));
          P.out[UNC_OFF + base + (r - 6)] = sp;
        }
      }
      sm.garr[tid] = acc;
      __syncthreads();
      // 2: LSTM[128:256] -> z2 h-part; x(t+1) -> zbn
      if (tid < 128) {
        float gi = sm.garr[tid], gf = sm.garr[128 + tid];
        float gg = sm.garr[256 + tid], go = sm.garr[384 + tid];
        float cn = sigf(gf) * c_r + sigf(gi) * tanhf(gg);
        c_r = cn;
        float h = sigf(go) * tanhf(cn);
        st16(sm.z2, 56 + tid, f16b(h));
      } else if (tid >= 192 && tid < 208) {
        int i = tid - 192;
        if (i < 13) {
          float xv = (t + 1 < T_) ? xb[(size_t)(t + 1) * DIN + i] : 0.f;
          st16(zbn, i, f16b(xv));
        }
      }
      __syncthreads();
      // 3: l2 partial over h2 quads (7..17 LDS, 18..22 streamed) — overlaps A's work
      float a2 = sm.cb2[tid];
#pragma unroll
      for (int q = 7; q < Q2LDS; ++q) a2 = dot8f(sm.l2w[q * NR2 + tid], sm.z2[q], a2);
#pragma unroll
      for (int q = Q2LDS; q < Q2; ++q) a2 = dot8f(P.wsL2[q * NR2 + tid], sm.z2[q], a2);
      // 4: poll hop1 {l0o, l1o} (tag+payload fused)
      if (tid < 128) {
        unsigned short v16 = axpoll(EX + X1O + tid, t + 1);
        if (tid < N0) {
          st16(zbn, 195 + tid, v16);
        } else {
          int j = tid - N0;
          st16(sm.z2, j, v16);
          st16(zbn, 144 + j, v16);
        }
      }
      __syncthreads();
      // 5: finish l2 (l1o quads 0..6, LDS)
#pragma unroll
      for (int q = 0; q < 7; ++q) a2 = dot8f(sm.l2w[q * NR2 + tid], sm.z2[q], a2);
      sm.ffb[tid] = (tid < 2 * N2) ? tanhf(a2) : a2;
      __syncthreads();
      // 6: combine l2 -> publish tagged
      if (tid < N2) {
        float ti = sigf(sm.ffb[2 * N2 + tid] + sm.ffb[3 * N2 + tid]);
        float v = sm.ffb[tid] * (1.f - ti) + ti * sm.ffb[N2 + tid];
        unsigned short v16 = f16b(v);
        axpub(EX + X2O + tid, t + 1, v16);
        st16(zbn, 16 + tid, v16);
      }
      __syncthreads();
      uint4* tmp = zbc; zbc = zbn; zbn = tmp;
    }
    // tail: heads for t = T_-1 (l2o in zbc after final swap)
    if (tid < 12) {
      int r = tid;
      float a = sm.hb[r];
#pragma unroll
      for (int q = 0; q < 16; ++q) a = dot8f(sm.hwq[r][q], zbc[2 + q], a);
      size_t base = ((size_t)b * T_ + (T_ - 1)) * 6;
      if (r < 6) P.out[base + r] = a;
      else {
        float sp = (a > 0.f) ? (a + log1pf(expf(-a))) : log1pf(expf(a));
        P.out[UNC_OFF + base + (r - 6)] = sp;
      }
    }
  }
}

// ================= fallback: direct f32 kernel (no workspace) =================

struct Args {
  const float* x;
  const float* Wih; const float* Whh; const float* bih; const float* bhh;
  const float* W0[4]; const float* b0[4]; const float* m0;
  const float* W1[4]; const float* b1[4]; const float* m1;
  const float* W2[4]; const float* b2[4]; const float* m2;
  const float* gW; const float* gb; const float* aW; const float* ab;
  const float* uW; const float* ub;
  float* out;
};

struct SMF {
  float xt[16];
  float lstm_h[HS];
  float hprev[HS];
  float garr[4 * HS];
  float ffb[4][128];
  float cb0[NR0];
  float cb1[NR1];
  float cb2[NR2];
  float hw[12][132];
  float hb[12];
};

__global__ __launch_bounds__(512, 2) void rnn_fallback(Args A) {
  extern __shared__ char smraw[];
  SMF& sm = *(SMF*)smraw;
  const int tid = threadIdx.x;
  const int b = blockIdx.x;

  for (int i = tid; i < NR0; i += 512) sm.cb0[i] = A.b0[i / N0][i % N0];
  for (int i = tid; i < NR1; i += 512) sm.cb1[i] = A.b1[i / N1][i % N1];
  for (int i = tid; i < NR2; i += 512) sm.cb2[i] = A.b2[i / N2][i % N2];
  for (int i = tid; i < 12 * 128; i += 512) {
    int r = i >> 7, k = i & 127;
    sm.hw[r][k] = (r < 3) ? A.gW[r * 128 + k]
                : (r < 6) ? A.aW[(r - 3) * 128 + k]
                          : A.uW[(r - 6) * 128 + k];
  }
  if (tid < 12) sm.hb[tid] = (tid < 3) ? A.gb[tid] : (tid < 6) ? A.ab[tid - 3] : A.ub[tid - 6];
  for (int i = tid; i < HS; i += 512) sm.hprev[i] = 0.f;
  float bga = A.bih[tid] + A.bhh[tid];
  float bgb = A.bih[tid + 512] + A.bhh[tid + 512];
  float c_r = 0.f;
  __syncthreads();

  const float* xb = A.x + (size_t)b * T_ * DIN;
  const size_t UNC_OFF = (size_t)B_ * T_ * 6;

  for (int t = 0; t < T_; ++t) {
    const float* xp = xb + (size_t)t * DIN;
    if (tid < DIN) sm.xt[tid] = xp[tid];
    __syncthreads();

    float aa = bga, ab = bgb;
    for (int k = 0; k < DIN; ++k) {
      float xv = sm.xt[k];
      aa += A.Wih[tid * DIN + k] * xv;
      ab += A.Wih[(tid + 512) * DIN + k] * xv;
    }
    for (int k = 0; k < HS; ++k) {
      float hv = sm.hprev[k];
      aa += A.Whh[tid * HS + k] * hv;
      ab += A.Whh[(tid + 512) * HS + k] * hv;
    }
    sm.garr[tid] = aa;
    sm.garr[tid + 512] = ab;
    __syncthreads();

    if (tid < HS) {
      float gi = sm.garr[tid], gf = sm.garr[HS + tid];
      float gg = sm.garr[2 * HS + tid], go = sm.garr[3 * HS + tid];
      float cn = sigf(gf) * c_r + sigf(gi) * tanhf(gg);
      c_r = cn;
      sm.lstm_h[tid] = sigf(go) * tanhf(cn);
    }
    __syncthreads();

    if (tid < NR0) {
      int mat = tid / N0, o = tid % N0;
      const float* W = A.W0[mat];
      const float* m = A.m0;
      const int Kl = DIN + N0;
      float acc = sm.cb0[tid];
      for (int k = 0; k < DIN; ++k) {
        float w = W[o * Kl + k];
        if (mat < 2) w *= m[o * Kl + k];
        acc += w * sm.xt[k];
      }
      for (int k = DIN; k < Kl; ++k) acc += W[o * Kl + k] * sm.lstm_h[k - DIN];
      sm.ffb[mat][o] = (mat < 2) ? tanhf(acc) : acc;
    }
    __syncthreads();
    if (tid < N0) {
      float ti = sigf(sm.ffb[2][tid] + sm.ffb[3][tid]);
      sm.hprev[tid] = sm.ffb[0][tid] * (1.f - ti) + ti * sm.ffb[1][tid];
    }
    __syncthreads();

    if (tid < NR1) {
      int mat = tid / N1, o = tid % N1;
      const float* W = A.W1[mat];
      const float* m = A.m1;
      const int Kl = N0 + N1;
      float acc = sm.cb1[tid];
      for (int k = 0; k < N0; ++k) {
        float w = W[o * Kl + k];
        if (mat < 2) w *= m[o * Kl + k];
        acc += w * sm.hprev[k];
      }
      for (int k = N0; k < Kl; ++k) acc += W[o * Kl + k] * sm.lstm_h[k];
      sm.ffb[mat][o] = (mat < 2) ? tanhf(acc) : acc;
    }
    __syncthreads();
    if (tid < N1) {
      float ti = sigf(sm.ffb[2][tid] + sm.ffb[3][tid]);
      sm.hprev[N0 + tid] = sm.ffb[0][tid] * (1.f - ti) + ti * sm.ffb[1][tid];
    }
    __syncthreads();

    {
      int mat = tid >> 7, o = tid & 127;
      const float* W = A.W2[mat];
      const float* m = A.m2;
      const int Kl = N1 + N2;
      float acc = sm.cb2[tid];
      for (int k = 0; k < N1; ++k) {
        float w = W[o * Kl + k];
        if (mat < 2) w *= m[o * Kl + k];
        acc += w * sm.hprev[N0 + k];
      }
      for (int k = N1; k < Kl; ++k) acc += W[o * Kl + k] * sm.lstm_h[N0 + k];
      sm.ffb[mat][o] = (mat < 2) ? tanhf(acc) : acc;
    }
    __syncthreads();
    if (tid < N2) {
      float ti = sigf(sm.ffb[2][tid] + sm.ffb[3][tid]);
      sm.hprev[N0 + N1 + tid] = sm.ffb[0][tid] * (1.f - ti) + ti * sm.ffb[1][tid];
    }
    __syncthreads();

    if (tid >= 256 && tid < 268) {
      int r = tid - 256;
      const float* mo = &sm.hprev[N0 + N1];
      float acc = sm.hb[r];
      for (int k = 0; k < 128; ++k) acc += sm.hw[r][k] * mo[k];
      size_t base = ((size_t)b * T_ + t) * 6;
      if (r < 6) A.out[base + r] = acc;
      else {
        float sp = (acc > 0.f) ? (acc + log1pf(expf(-acc))) : log1pf(expf(acc));
        A.out[UNC_OFF + base + (r - 6)] = sp;
      }
    }
    __syncthreads();
  }
}

// ---------------- launcher ----------------

extern "C" void kernel_launch(void* const* d_in, const int* in_sizes, int n_in,
                              void* d_out, int out_size, void* d_ws, size_t ws_size,
                              hipStream_t stream) {
  const float* x   = (const float*)d_in[0];
  const float* Wih = (const float*)d_in[1];
  const float* Whh = (const float*)d_in[2];
  const float* bih = (const float*)d_in[3];
  const float* bhh = (const float*)d_in[4];
  const float *W[3][4], *bb[3][4], *mk[3];
  for (int l = 0; l < 3; ++l) {
    int base = 5 + l * 9;
    for (int nm = 0; nm < 4; ++nm) {
      W[l][nm]  = (const float*)d_in[base + 2 * nm];
      bb[l][nm] = (const float*)d_in[base + 2 * nm + 1];
    }
    mk[l] = (const float*)d_in[base + 8];
  }
  const float* gW = (const float*)d_in[32];
  const float* gb = (const float*)d_in[33];
  const float* aW = (const float*)d_in[34];
  const float* ab = (const float*)d_in[35];
  const float* uW = (const float*)d_in[36];
  const float* ub = (const float*)d_in[37];

  char* ws = (char*)d_ws;
  const size_t szG  = (size_t)QG * NRG * 16;   // 557056
  const size_t szL0 = (size_t)Q0 * NR0 * 16;   // 59136
  const size_t szL1 = (size_t)Q1 * NR1 * 16;   // 52224
  const size_t szL2 = (size_t)Q2 * NR2 * 16;   // 188416
  const size_t offG = 0, offL0 = szG, offL1 = offL0 + szL0, offL2 = offL1 + szL1;
  const size_t offEx = offL2 + szL2;           // 856832
  const size_t exBytes = (size_t)B_ * EXSTRIDE * 4;  // 131072
  const size_t need = offEx + exBytes;         // 987904

  if (ws_size >= need) {
    PArgs P;
    P.x = x; P.bih = bih; P.bhh = bhh;
    for (int nm = 0; nm < 4; ++nm) { P.b0[nm] = bb[0][nm]; P.b1[nm] = bb[1][nm]; P.b2[nm] = bb[2][nm]; }
    P.gW = gW; P.gb = gb; P.aW = aW; P.ab = ab; P.uW = uW; P.ub = ub;
    P.wsG  = (const uint4*)(ws + offG);
    P.wsL0 = (const uint4*)(ws + offL0);
    P.wsL1 = (const uint4*)(ws + offL1);
    P.wsL2 = (const uint4*)(ws + offL2);
    P.ex   = (int*)(ws + offEx);
    P.out  = (float*)d_out;

    hipMemsetAsync(ws + offEx, 0, exBytes, stream);   // reset tags each launch/replay
    int n;
    n = 136 * NRG;
    prep_gates3<<<(n + 255) / 256, 256, 0, stream>>>(Wih, Whh, (uint32_t*)(ws + offG));
    n = NR0 * 48;
    prep_cfc2<<<(n + 255) / 256, 256, 0, stream>>>(W[0][0], W[0][1], W[0][2], W[0][3], mk[0],
                                                   N0, DIN + N0, NR0, 48,
                                                   90, 0, 96, 0, 0,
                                                   (uint32_t*)(ws + offL0));
    n = NR1 * 64;
    prep_cfc2<<<(n + 255) / 256, 256, 0, stream>>>(W[1][0], W[1][1], W[1][2], W[1][3], mk[1],
                                                   N1, N0 + N1, NR1, 64,
                                                   51, 77, 51, 77, 0,
                                                   (uint32_t*)(ws + offL1));
    n = NR2 * 92;
    prep_cfc2<<<(n + 255) / 256, 256, 0, stream>>>(W[2][0], W[2][1], W[2][2], W[2][3], mk[2],
                                                   N2, N1 + N2, NR2, 92,
                                                   51, 0, 56, 128, 51,
                                                   (uint32_t*)(ws + offL2));
    int lds = (int)((sizeof(SMA) > sizeof(SMB)) ? sizeof(SMA) : sizeof(SMB));
    hipFuncSetAttribute(reinterpret_cast<const void*>(&rnn_coop3),
                        hipFuncAttributeMaxDynamicSharedMemorySize, lds);
    rnn_coop3<<<2 * B_, 512, lds, stream>>>(P);
    return;
  }

  // -------- fallback: direct f32 --------
  Args A;
  A.x = x; A.Wih = Wih; A.Whh = Whh; A.bih = bih; A.bhh = bhh;
  for (int nm = 0; nm < 4; ++nm) {
    A.W0[nm] = W[0][nm]; A.b0[nm] = bb[0][nm];
    A.W1[nm] = W[1][nm]; A.b1[nm] = bb[1][nm];
    A.W2[nm] = W[2][nm]; A.b2[nm] = bb[2][nm];
  }
  A.m0 = mk[0]; A.m1 = mk[1]; A.m2 = mk[2];
  A.gW = gW; A.gb = gb; A.aW = aW; A.ab = ab; A.uW = uW; A.ub = ub;
  A.out = (float*)d_out;
  hipFuncSetAttribute(reinterpret_cast<const void*>(&rnn_fallback),
                      hipFuncAttributeMaxDynamicSharedMemorySize, (int)sizeof(SMF));
  rnn_fallback<<<B_, 512, sizeof(SMF), stream>>>(A);
}